// Round 2
// baseline (200.198 us; speedup 1.0000x reference)
//
#include <hip/hip_runtime.h>
#include <hip/hip_bf16.h>

// ModuleCorefProp2: coref propagation, B=1, K=512, N=16384, D=512, H=64, NB=10, 1 iter.
// R2: k_pair rebuilt — per-WG one j, B-panel built once into LDS, A fragments
// straight from global (L2), barrier-free K-loop, 2 WGs/CU.

typedef __bf16 bf16;
typedef bf16 bf16x8 __attribute__((ext_vector_type(8)));
typedef float f32x4 __attribute__((ext_vector_type(4)));

#define MFMA16(a, b, c) __builtin_amdgcn_mfma_f32_16x16x32_bf16((a), (b), (c), 0, 0, 0)

// ---------------------------------------------------------------- prep
__global__ void k_prep(const float* __restrict__ sv,
                       const float* __restrict__ Wl, const float* __restrict__ Wr,
                       const float* __restrict__ Wg1, const float* __restrict__ Wg2,
                       const float* __restrict__ de, const float* __restrict__ Wd,
                       const float* __restrict__ bd, const float* __restrict__ bl,
                       const float* __restrict__ br, const float* __restrict__ bg1,
                       const float* __restrict__ bg2, const float* __restrict__ Wp,
                       bf16* __restrict__ u1, bf16* __restrict__ ugb,
                       bf16* __restrict__ wlr, float* __restrict__ blbr,
                       float* __restrict__ bgc, bf16* __restrict__ wgb,
                       float* __restrict__ dtab, float* __restrict__ wpT)
{
  const int total = 262144 + 65536 + 128 + 1048576 + 1024 + 640 + 32768;
  for (int idx0 = blockIdx.x * 256 + threadIdx.x; idx0 < total; idx0 += 2048 * 256) {
    int k = idx0;
    if (k < 262144) {                 // u -> bf16, and left halves of gate inputs
      float v = sv[k]; bf16 b = (bf16)v; u1[k] = b;
      int i = k >> 9, d = k & 511;
      ugb[(long)i * 1024 + d] = b;
      ugb[524288 + (long)i * 1024 + d] = b;
      continue;
    }
    k -= 262144;
    if (k < 65536) {                  // Wlr = [Wl | Wr] bf16 [512][128]
      int d = k >> 7, h = k & 127;
      wlr[k] = (bf16)(h < 64 ? Wl[d * 64 + h] : Wr[d * 64 + h - 64]);
      continue;
    }
    k -= 65536;
    if (k < 128) { blbr[k] = (k < 64 ? bl[k] : br[k - 64]); continue; }
    k -= 128;
    if (k < 1048576) {                // Wg1|Wg2 bf16 [2][1024][512]
      wgb[k] = (bf16)(k < 524288 ? Wg1[k] : Wg2[k - 524288]);
      continue;
    }
    k -= 1048576;
    if (k < 1024) { bgc[k] = (k < 512 ? bg1[k] : bg2[k - 512]); continue; }
    k -= 1024;
    if (k < 640) {                    // dtab[NB][64] = dist_emb@Wd + bd
      int b_ = k >> 6, h = k & 63;
      float s = bd[h];
      for (int e = 0; e < 64; ++e) s += de[b_ * 64 + e] * Wd[e * 64 + h];
      dtab[k] = s;
      continue;
    }
    k -= 640;
    {                                 // WpT[h][d] = Wp[d][h], f32 [64][512]
      int h = k >> 9, d = k & 511;
      wpT[k] = Wp[d * 64 + h];
    }
  }
}

// ---------------------------------------------------------------- generic GEMM
// C[M,N] = A[M,K](bf16) @ B[K,N](bf16) (+bias), 64x64 tiles, 4 waves of 32x32.
__global__ __launch_bounds__(256, 2) void k_gemm(
    const bf16* __restrict__ A, int lda, long asz,
    const bf16* __restrict__ B, int ldb, long bsz,
    float* __restrict__ C, int ldc, long csz,
    const float* __restrict__ bias, int bstride, int K)
{
  __shared__ bf16 As[64 * 40];
  __shared__ bf16 Bs[64 * 40];
  const int t = threadIdx.x, lane = t & 63, wave = t >> 6;
  const int tc = blockIdx.x, tr = blockIdx.y, z = blockIdx.z;
  A += (long)z * asz; B += (long)z * bsz; C += (long)z * csz;
  const int wr = wave >> 1, wc = wave & 1;
  const int arow = t >> 2, aslot = t & 3;
  const int s = lane >> 4, rr = lane & 15;
  f32x4 acc00 = {}, acc01 = {}, acc10 = {}, acc11 = {};
  const int nk = K >> 5;
  for (int kk = 0; kk < nk; ++kk) {
    __syncthreads();
    *(uint4*)&As[arow * 40 + aslot * 8] =
        *(const uint4*)(A + (long)(tr * 64 + arow) * lda + kk * 32 + aslot * 8);
    {
      const bf16* bsrc = B + (long)(kk * 32 + aslot * 8) * ldb + tc * 64 + arow;
      bf16x8 tv;
#pragma unroll
      for (int e = 0; e < 8; ++e) tv[e] = bsrc[(long)e * ldb];
      *(bf16x8*)&Bs[arow * 40 + aslot * 8] = tv;
    }
    __syncthreads();
    bf16x8 a0 = *(const bf16x8*)&As[(wr * 32 + rr) * 40 + s * 8];
    bf16x8 a1 = *(const bf16x8*)&As[(wr * 32 + 16 + rr) * 40 + s * 8];
    bf16x8 b0 = *(const bf16x8*)&Bs[(wc * 32 + rr) * 40 + s * 8];
    bf16x8 b1 = *(const bf16x8*)&Bs[(wc * 32 + 16 + rr) * 40 + s * 8];
    acc00 = MFMA16(a0, b0, acc00);
    acc01 = MFMA16(a0, b1, acc01);
    acc10 = MFMA16(a1, b0, acc10);
    acc11 = MFMA16(a1, b1, acc11);
  }
#pragma unroll
  for (int mf = 0; mf < 2; ++mf) {
#pragma unroll
    for (int nf = 0; nf < 2; ++nf) {
      f32x4 v = mf == 0 ? (nf == 0 ? acc00 : acc01) : (nf == 0 ? acc10 : acc11);
      int col = tc * 64 + wc * 32 + nf * 16 + rr;
      float bi = bias ? bias[z * bstride + col] : 0.f;
      int row0 = tr * 64 + wr * 32 + mf * 16 + s * 4;
#pragma unroll
      for (int r = 0; r < 4; ++r)
        C[(long)(row0 + r) * ldc + col] = v[r] + bi;
    }
  }
}

// ---------------------------------------------------------------- fused pair scorer (R2)
// Grid 512 (one j per WG), 256 threads = 4 waves, wave wm handles i0 = wm*128.
// Prologue: Bs[h][d] = u_j[d]*WpT[h][d] (bf16, rows padded to 520), one barrier.
// K-loop: A fragments from global (L2), double-buffered regs; B from LDS; no barriers.
__global__ __launch_bounds__(256, 2) void k_pair(
    const bf16* __restrict__ Ubf, const float* __restrict__ Uf,
    const float* __restrict__ WpT, const float* __restrict__ LR,
    const float* __restrict__ dtabg, const int* __restrict__ sb,
    const float* __restrict__ ss, const float* __restrict__ Wo,
    const float* __restrict__ bo, float* __restrict__ cs)
{
  __shared__ bf16 Bs[64 * 520];     // B_j^T panel [h][d], rows padded to 520
  __shared__ float dts[640];

  const int t = threadIdx.x;
  const int lane = t & 63;
  const int wave = t >> 6;
  const int j = blockIdx.x;
  const int s = lane >> 4, rr = lane & 15;
  const int i0 = wave * 128;

  // ---- prologue: build B_j^T into LDS (4096 bf16x8 chunks over 256 threads)
  const float* ujrow = Uf + (long)j * 512;
#pragma unroll
  for (int it = 0; it < 16; ++it) {
    int idx8 = it * 256 + t;          // chunk id: h = idx8>>6, dblk = idx8&63
    int h = idx8 >> 6, d0 = (idx8 & 63) * 8;
    float4 w0 = *(const float4*)(WpT + h * 512 + d0);
    float4 w1 = *(const float4*)(WpT + h * 512 + d0 + 4);
    float4 uu0 = *(const float4*)(ujrow + d0);
    float4 uu1 = *(const float4*)(ujrow + d0 + 4);
    bf16x8 bv;
    bv[0] = (bf16)(w0.x * uu0.x); bv[1] = (bf16)(w0.y * uu0.y);
    bv[2] = (bf16)(w0.z * uu0.z); bv[3] = (bf16)(w0.w * uu0.w);
    bv[4] = (bf16)(w1.x * uu1.x); bv[5] = (bf16)(w1.y * uu1.y);
    bv[6] = (bf16)(w1.z * uu1.z); bv[7] = (bf16)(w1.w * uu1.w);
    *(bf16x8*)&Bs[h * 520 + d0] = bv;
  }
  for (int idx = t; idx < 640; idx += 256) dts[idx] = dtabg[idx];
  __syncthreads();

  // ---- K-loop
  f32x4 acc[8][4] = {};
  uint4 a0[8], a1[8];
  const bf16* abase = Ubf + (long)(i0 + rr) * 512 + s * 8;

#pragma unroll
  for (int mf = 0; mf < 8; ++mf)
    a0[mf] = *(const uint4*)(abase + mf * 16 * 512);

#pragma unroll
  for (int kk = 0; kk < 16; kk += 2) {
    // prefetch kk+1 into a1
#pragma unroll
    for (int mf = 0; mf < 8; ++mf)
      a1[mf] = *(const uint4*)(abase + mf * 16 * 512 + (kk + 1) * 32);
    {
      bf16x8 b[4];
#pragma unroll
      for (int hf = 0; hf < 4; ++hf)
        b[hf] = *(const bf16x8*)&Bs[(hf * 16 + rr) * 520 + kk * 32 + s * 8];
#pragma unroll
      for (int hf = 0; hf < 4; ++hf)
#pragma unroll
        for (int mf = 0; mf < 8; ++mf)
          acc[mf][hf] = MFMA16(*(const bf16x8*)&a0[mf], b[hf], acc[mf][hf]);
    }
    // prefetch kk+2 into a0
    if (kk + 2 < 16) {
#pragma unroll
      for (int mf = 0; mf < 8; ++mf)
        a0[mf] = *(const uint4*)(abase + mf * 16 * 512 + (kk + 2) * 32);
    }
    {
      bf16x8 b[4];
#pragma unroll
      for (int hf = 0; hf < 4; ++hf)
        b[hf] = *(const bf16x8*)&Bs[(hf * 16 + rr) * 520 + (kk + 1) * 32 + s * 8];
#pragma unroll
      for (int hf = 0; hf < 4; ++hf)
#pragma unroll
        for (int mf = 0; mf < 8; ++mf)
          acc[mf][hf] = MFMA16(*(const bf16x8*)&a1[mf], b[hf], acc[mf][hf]);
    }
  }

  // ---- epilogue: cs[i][j] = (i==j)?0 : sum_h Wo[h]*relu(prod+left+right+dist)+bo+ss[i]+ss[j]
  float wo4[4], rj4[4];
#pragma unroll
  for (int hf = 0; hf < 4; ++hf) {
    wo4[hf] = Wo[hf * 16 + rr];
    rj4[hf] = LR[j * 128 + 64 + hf * 16 + rr];
  }
  const int sbj = sb[j];
  const float ssj = ss[j];
  const float bo0 = bo[0];
#pragma unroll
  for (int mf = 0; mf < 8; ++mf) {
#pragma unroll
    for (int r = 0; r < 4; ++r) {
      int i = i0 + mf * 16 + s * 4 + r;
      int dd = sb[i] - sbj;
      int ad = dd < 0 ? -dd : dd;
      int bkt = ad < 5 ? ad : (31 - __clz(ad)) + 3;
      bkt = bkt > 9 ? 9 : bkt;
      float sum = 0.f;
#pragma unroll
      for (int hf = 0; hf < 4; ++hf) {
        float v = acc[mf][hf][r] + LR[i * 128 + hf * 16 + rr] + rj4[hf] +
                  dts[bkt * 64 + hf * 16 + rr];
        v = fmaxf(v, 0.f);
        sum += v * wo4[hf];
      }
      sum += __shfl_xor(sum, 1);
      sum += __shfl_xor(sum, 2);
      sum += __shfl_xor(sum, 4);
      sum += __shfl_xor(sum, 8);
      if (rr == 0) {
        float val = (i == j) ? 0.f : (sum + bo0 + ss[i] + ssj);
        cs[i * 512 + j] = val;
      }
    }
  }
}

// ---------------------------------------------------------------- masked softmax rows
__global__ __launch_bounds__(64) void k_softmax(const float* __restrict__ cs,
                                                bf16* __restrict__ p12)
{
  int b = blockIdx.x, kind = b >> 9, i = b & 511, lane = threadIdx.x;
  const float* row = cs + i * 512;
  float v[8];
  float4 x0 = *(const float4*)(row + lane * 8);
  float4 x1 = *(const float4*)(row + lane * 8 + 4);
  v[0] = x0.x; v[1] = x0.y; v[2] = x0.z; v[3] = x0.w;
  v[4] = x1.x; v[5] = x1.y; v[6] = x1.z; v[7] = x1.w;
  bool any = (kind == 0) ? (i > 0) : (i < 511);
  bf16x8 ov;
  if (!any) {
    float u = 1.0f / 512.0f;
#pragma unroll
    for (int e = 0; e < 8; ++e) ov[e] = (bf16)u;
  } else {
    float m = -3.4e38f;
#pragma unroll
    for (int e = 0; e < 8; ++e) {
      int jj = lane * 8 + e;
      bool valid = (kind == 0) ? (jj < i) : (jj > i);
      if (valid) m = fmaxf(m, v[e]);
    }
    m = fmaxf(m, __shfl_xor(m, 1));  m = fmaxf(m, __shfl_xor(m, 2));
    m = fmaxf(m, __shfl_xor(m, 4));  m = fmaxf(m, __shfl_xor(m, 8));
    m = fmaxf(m, __shfl_xor(m, 16)); m = fmaxf(m, __shfl_xor(m, 32));
    float p[8]; float ssum = 0.f;
#pragma unroll
    for (int e = 0; e < 8; ++e) {
      int jj = lane * 8 + e;
      bool valid = (kind == 0) ? (jj < i) : (jj > i);
      p[e] = valid ? __expf(v[e] - m) : 0.f;
      ssum += p[e];
    }
    ssum += __shfl_xor(ssum, 1);  ssum += __shfl_xor(ssum, 2);
    ssum += __shfl_xor(ssum, 4);  ssum += __shfl_xor(ssum, 8);
    ssum += __shfl_xor(ssum, 16); ssum += __shfl_xor(ssum, 32);
    float inv = 1.0f / ssum;
#pragma unroll
    for (int e = 0; e < 8; ++e) ov[e] = (bf16)(p[e] * inv);
  }
  *(bf16x8*)(p12 + (long)b * 512 + lane * 8) = ov;
}

// ---------------------------------------------------------------- gate input build
__global__ void k_gatein(const float* __restrict__ c12, bf16* __restrict__ ugb)
{
  for (int idx = blockIdx.x * 256 + threadIdx.x; idx < 262144; idx += 512 * 256) {
    int i = idx >> 9, d = idx & 511;
    ugb[(long)i * 1024 + 512 + d] = (bf16)c12[idx];
    ugb[524288 + (long)i * 1024 + 512 + d] = (bf16)c12[262144 + idx];
  }
}

// ---------------------------------------------------------------- gates + update
__global__ void k_gate(const float* __restrict__ sv, const float* __restrict__ c12,
                       const float* __restrict__ G12, float* __restrict__ upd,
                       bf16* __restrict__ u2)
{
  for (int idx = blockIdx.x * 256 + threadIdx.x; idx < 262144; idx += 512 * 256) {
    float u = sv[idx], c1 = c12[idx], c2 = c12[262144 + idx];
    float g1 = 1.f / (1.f + __expf(-G12[idx]));
    float g2 = 1.f / (1.f + __expf(-G12[262144 + idx]));
    float up = g1 * u + (1.f - g1) * c1 + g2 * u + (1.f - g2) * c2;
    upd[idx] = up;
    u2[idx] = (bf16)up;
  }
}

// ---------------------------------------------------------------- ss2 = update@Wpr + bpr
__global__ __launch_bounds__(64) void k_ss2(const float* __restrict__ upd,
                                            const float* __restrict__ Wpr,
                                            const float* __restrict__ bpr,
                                            float* __restrict__ ss2)
{
  int row = blockIdx.x, lane = threadIdx.x;
  const float* rp = upd + row * 512 + lane * 8;
  const float* wp = Wpr + lane * 8;
  float4 a0 = *(const float4*)rp, a1 = *(const float4*)(rp + 4);
  float4 b0 = *(const float4*)wp, b1 = *(const float4*)(wp + 4);
  float s = a0.x * b0.x + a0.y * b0.y + a0.z * b0.z + a0.w * b0.w +
            a1.x * b1.x + a1.y * b1.y + a1.z * b1.z + a1.w * b1.w;
  s += __shfl_xor(s, 1);  s += __shfl_xor(s, 2);  s += __shfl_xor(s, 4);
  s += __shfl_xor(s, 8);  s += __shfl_xor(s, 16); s += __shfl_xor(s, 32);
  if (lane == 0) ss2[row] = s + bpr[0];
}

// ---------------------------------------------------------------- all_out assembly
__global__ void k_copy(const float* __restrict__ in, float* __restrict__ out)
{
  const float4* i4 = (const float4*)in;
  float4* o4 = (float4*)out;
  for (int idx = blockIdx.x * 256 + threadIdx.x; idx < 2097152; idx += 2048 * 256)
    o4[idx] = i4[idx];
}

__global__ __launch_bounds__(64) void k_scatter(const float* __restrict__ upd,
                                                const int* __restrict__ pi,
                                                const int* __restrict__ sl,
                                                float* __restrict__ out)
{
  int k = blockIdx.x;
  if (k >= sl[0]) return;
  int dst = pi[k];
  int lane = threadIdx.x;
  const float4* s4 = (const float4*)(upd + k * 512);
  float4* d4 = (float4*)(out + (long)dst * 512);
  d4[lane * 2] = s4[lane * 2];
  d4[lane * 2 + 1] = s4[lane * 2 + 1];
}

// ---------------------------------------------------------------- launch
extern "C" void kernel_launch(void* const* d_in, const int* in_sizes, int n_in,
                              void* d_out, int out_size, void* d_ws, size_t ws_size,
                              hipStream_t stream)
{
  const float* asv = (const float*)d_in[0];
  const float* sv = (const float*)d_in[1];
  const int* sb = (const int*)d_in[2];
  const float* sscore = (const float*)d_in[5];
  const int* pi = (const int*)d_in[6];
  const int* sl = (const int*)d_in[7];
  const float* Wl = (const float*)d_in[9];
  const float* bl = (const float*)d_in[10];
  const float* Wr = (const float*)d_in[11];
  const float* br = (const float*)d_in[12];
  const float* Wp = (const float*)d_in[13];
  const float* de = (const float*)d_in[14];
  const float* Wd = (const float*)d_in[15];
  const float* bd = (const float*)d_in[16];
  const float* Wo = (const float*)d_in[17];
  const float* bo = (const float*)d_in[18];
  const float* Wg1 = (const float*)d_in[19];
  const float* bg1 = (const float*)d_in[20];
  const float* Wg2 = (const float*)d_in[21];
  const float* bg2 = (const float*)d_in[22];
  const float* Wpr = (const float*)d_in[23];
  const float* bpr = (const float*)d_in[24];

  float* out_all = (float*)d_out;
  float* out_upd = out_all + 8388608;   // [512][512] update
  float* out_cs = out_all + 8650752;    // [512][512] cs

  char* w = (char*)d_ws;
  size_t off = 0;
  auto take = [&](size_t bytes) -> void* {
    void* p = w + off;
    off = (off + bytes + 255) & ~(size_t)255;
    return p;
  };
  bf16* u1b = (bf16*)take(524288);
  bf16* u2b = (bf16*)take(524288);
  bf16* wlr = (bf16*)take(131072);
  bf16* wgb = (bf16*)take(2097152);
  float* blbr = (float*)take(512);
  float* bgc = (float*)take(4096);
  float* dtab = (float*)take(2560);
  float* wpT = (float*)take(131072);
  float* lr1 = (float*)take(262144);
  float* lr2 = (float*)take(262144);
  float* cs1 = (float*)take(1048576);
  bf16* p12 = (bf16*)take(1048576);
  float* c12 = (float*)take(4194304);
  bf16* ugb = (bf16*)take(2097152);
  float* G12 = (float*)take(2097152);
  float* ss2 = (float*)take(2048);

  k_prep<<<2048, 256, 0, stream>>>(sv, Wl, Wr, Wg1, Wg2, de, Wd, bd, bl, br, bg1, bg2,
                                   Wp, u1b, ugb, wlr, blbr, bgc, wgb, dtab, wpT);
  // left|right for u
  k_gemm<<<dim3(2, 8, 1), 256, 0, stream>>>(u1b, 512, 0, wlr, 128, 0, lr1, 128, 0,
                                            blbr, 0, 512);
  // cs1 = add_scores(pair_scores(u), span_scores)
  k_pair<<<512, 256, 0, stream>>>(u1b, sv, wpT, lr1, dtab, sb, sscore, Wo, bo, cs1);
  // p1,p2
  k_softmax<<<1024, 64, 0, stream>>>(cs1, p12);
  // c1,c2 = [p1;p2] @ u
  k_gemm<<<dim3(8, 16, 1), 256, 0, stream>>>(p12, 512, 0, u1b, 512, 0, c12, 512, 0,
                                             nullptr, 0, 512);
  k_gatein<<<512, 256, 0, stream>>>(c12, ugb);
  // G1,G2 = [u|c] @ Wg + bg   (batched z=2, K=1024)
  k_gemm<<<dim3(8, 8, 2), 256, 0, stream>>>(ugb, 1024, 524288, wgb, 512, 524288,
                                            G12, 512, 262144, bgc, 512, 1024);
  k_gate<<<512, 256, 0, stream>>>(sv, c12, G12, out_upd, u2b);
  k_ss2<<<512, 64, 0, stream>>>(out_upd, Wpr, bpr, ss2);
  // left|right for update
  k_gemm<<<dim3(2, 8, 1), 256, 0, stream>>>(u2b, 512, 0, wlr, 128, 0, lr2, 128, 0,
                                            blbr, 0, 512);
  // cs = add_scores(pair_scores(update), update@Wpr+bpr)
  k_pair<<<512, 256, 0, stream>>>(u2b, out_upd, wpT, lr2, dtab, sb, ss2, Wo, bo, out_cs);
  // all_out
  k_copy<<<2048, 256, 0, stream>>>(asv, out_all);
  k_scatter<<<512, 64, 0, stream>>>(out_upd, pi, sl, out_all);
}

// Round 3
// 182.389 us; speedup vs baseline: 1.0976x; 1.0976x over previous
//
#include <hip/hip_runtime.h>
#include <hip/hip_bf16.h>

// ModuleCorefProp2: coref propagation, B=1, K=512, N=16384, D=512, H=64, NB=10, 1 iter.
// R3: k_pair rebuilt for occupancy: 256-thr WGs, 37KB LDS -> 4 WGs/CU (16 waves),
// 32x32x16 MFMA, rows=j cols=(i,h) (contiguous cs writes), k-chunk double-buffer,
// one barrier per chunk, B=u_i*Wp built in registers.

typedef __bf16 bf16;
typedef bf16 bf16x8 __attribute__((ext_vector_type(8)));
typedef float f32x4 __attribute__((ext_vector_type(4)));
typedef float f32x16 __attribute__((ext_vector_type(16)));

#define MFMA16(a, b, c) __builtin_amdgcn_mfma_f32_16x16x32_bf16((a), (b), (c), 0, 0, 0)
#define MFMA32(a, b, c) __builtin_amdgcn_mfma_f32_32x32x16_bf16((a), (b), (c), 0, 0, 0)

// ---------------------------------------------------------------- prep
__global__ void k_prep(const float* __restrict__ sv,
                       const float* __restrict__ Wl, const float* __restrict__ Wr,
                       const float* __restrict__ Wg1, const float* __restrict__ Wg2,
                       const float* __restrict__ de, const float* __restrict__ Wd,
                       const float* __restrict__ bd, const float* __restrict__ bl,
                       const float* __restrict__ br, const float* __restrict__ bg1,
                       const float* __restrict__ bg2, const float* __restrict__ Wp,
                       bf16* __restrict__ u1, bf16* __restrict__ ugb,
                       bf16* __restrict__ wlr, float* __restrict__ blbr,
                       float* __restrict__ bgc, bf16* __restrict__ wgb,
                       float* __restrict__ dtab, bf16* __restrict__ wpTb)
{
  const int total = 262144 + 65536 + 128 + 1048576 + 1024 + 640 + 32768;
  for (int idx0 = blockIdx.x * 256 + threadIdx.x; idx0 < total; idx0 += 2048 * 256) {
    int k = idx0;
    if (k < 262144) {                 // u -> bf16, and left halves of gate inputs
      float v = sv[k]; bf16 b = (bf16)v; u1[k] = b;
      int i = k >> 9, d = k & 511;
      ugb[(long)i * 1024 + d] = b;
      ugb[524288 + (long)i * 1024 + d] = b;
      continue;
    }
    k -= 262144;
    if (k < 65536) {                  // Wlr = [Wl | Wr] bf16 [512][128]
      int d = k >> 7, h = k & 127;
      wlr[k] = (bf16)(h < 64 ? Wl[d * 64 + h] : Wr[d * 64 + h - 64]);
      continue;
    }
    k -= 65536;
    if (k < 128) { blbr[k] = (k < 64 ? bl[k] : br[k - 64]); continue; }
    k -= 128;
    if (k < 1048576) {                // Wg1|Wg2 bf16 [2][1024][512]
      wgb[k] = (bf16)(k < 524288 ? Wg1[k] : Wg2[k - 524288]);
      continue;
    }
    k -= 1048576;
    if (k < 1024) { bgc[k] = (k < 512 ? bg1[k] : bg2[k - 512]); continue; }
    k -= 1024;
    if (k < 640) {                    // dtab[NB][64] = dist_emb@Wd + bd
      int b_ = k >> 6, h = k & 63;
      float s = bd[h];
      for (int e = 0; e < 64; ++e) s += de[b_ * 64 + e] * Wd[e * 64 + h];
      dtab[k] = s;
      continue;
    }
    k -= 640;
    {                                 // wpTb[h][d] = Wp[d][h], bf16 [64][512]
      int h = k >> 9, d = k & 511;
      wpTb[k] = (bf16)Wp[d * 64 + h];
    }
  }
}

// ---------------------------------------------------------------- generic GEMM
// C[M,N] = A[M,K](bf16) @ B[K,N](bf16) (+bias), 64x64 tiles, 4 waves of 32x32.
__global__ __launch_bounds__(256, 2) void k_gemm(
    const bf16* __restrict__ A, int lda, long asz,
    const bf16* __restrict__ B, int ldb, long bsz,
    float* __restrict__ C, int ldc, long csz,
    const float* __restrict__ bias, int bstride, int K)
{
  __shared__ bf16 As[64 * 40];
  __shared__ bf16 Bs[64 * 40];
  const int t = threadIdx.x, lane = t & 63, wave = t >> 6;
  const int tc = blockIdx.x, tr = blockIdx.y, z = blockIdx.z;
  A += (long)z * asz; B += (long)z * bsz; C += (long)z * csz;
  const int wr = wave >> 1, wc = wave & 1;
  const int arow = t >> 2, aslot = t & 3;
  const int s = lane >> 4, rr = lane & 15;
  f32x4 acc00 = {}, acc01 = {}, acc10 = {}, acc11 = {};
  const int nk = K >> 5;
  for (int kk = 0; kk < nk; ++kk) {
    __syncthreads();
    *(uint4*)&As[arow * 40 + aslot * 8] =
        *(const uint4*)(A + (long)(tr * 64 + arow) * lda + kk * 32 + aslot * 8);
    {
      const bf16* bsrc = B + (long)(kk * 32 + aslot * 8) * ldb + tc * 64 + arow;
      bf16x8 tv;
#pragma unroll
      for (int e = 0; e < 8; ++e) tv[e] = bsrc[(long)e * ldb];
      *(bf16x8*)&Bs[arow * 40 + aslot * 8] = tv;
    }
    __syncthreads();
    bf16x8 a0 = *(const bf16x8*)&As[(wr * 32 + rr) * 40 + s * 8];
    bf16x8 a1 = *(const bf16x8*)&As[(wr * 32 + 16 + rr) * 40 + s * 8];
    bf16x8 b0 = *(const bf16x8*)&Bs[(wc * 32 + rr) * 40 + s * 8];
    bf16x8 b1 = *(const bf16x8*)&Bs[(wc * 32 + 16 + rr) * 40 + s * 8];
    acc00 = MFMA16(a0, b0, acc00);
    acc01 = MFMA16(a0, b1, acc01);
    acc10 = MFMA16(a1, b0, acc10);
    acc11 = MFMA16(a1, b1, acc11);
  }
#pragma unroll
  for (int mf = 0; mf < 2; ++mf) {
#pragma unroll
    for (int nf = 0; nf < 2; ++nf) {
      f32x4 v = mf == 0 ? (nf == 0 ? acc00 : acc01) : (nf == 0 ? acc10 : acc11);
      int col = tc * 64 + wc * 32 + nf * 16 + rr;
      float bi = bias ? bias[z * bstride + col] : 0.f;
      int row0 = tr * 64 + wr * 32 + mf * 16 + s * 4;
#pragma unroll
      for (int r = 0; r < 4; ++r)
        C[(long)(row0 + r) * ldc + col] = v[r] + bi;
    }
  }
}

// ---------------------------------------------------------------- fused pair scorer (R3)
// prod[i,j,h] = sum_d u[i,d]*u[j,d]*Wp[d,h]; rows = j (128/WG), cols = (i,h) (2 i * 64 h).
// Grid: x = 256 i-pairs, y = 4 j-blocks. 256 thr = 4 waves: wjj = wave>>1 (64-row half),
// wii = wave&1 (which i). 32x32x16 MFMA; per wave acc[mf=2][hf=2] f32x16.
// LDS: A(u j-rows) chunk dbuf 2x[128][40], Wp chunk dbuf 2x[64][40], u_i f32 [2][512], dts.
__global__ __launch_bounds__(256, 4) void k_pair(
    const bf16* __restrict__ Ubf, const float* __restrict__ Uf,
    const bf16* __restrict__ wpTb, const float* __restrict__ LR,
    const float* __restrict__ dtabg, const int* __restrict__ sb,
    const float* __restrict__ ss, const float* __restrict__ Wo,
    const float* __restrict__ bo, float* __restrict__ cs)
{
  __shared__ bf16 Ab[2][128 * 40];
  __shared__ bf16 Wb[2][64 * 40];
  __shared__ float usl[2][512];
  __shared__ float dts[640];

  const int t = threadIdx.x;
  const int lane = t & 63;
  const int wave = t >> 6;
  const int wjj = wave >> 1;        // j-row half (0/1)
  const int wii = wave & 1;         // which i (0/1)
  const int i0 = blockIdx.x * 2;
  const int jbase = blockIdx.y * 128;
  const int lh = lane & 31;
  const int half = lane >> 5;

  // staging index precompute
  const int arow = t >> 1, ahalf = (t & 1) * 16;       // A: 128 rows x 64B
  const bf16* asrc0 = Ubf + (long)(jbase + arow) * 512 + ahalf;
  bf16* adst = &Ab[0][arow * 40 + ahalf];
  const int wrow = t >> 2, wq = (t & 3) * 8;           // Wp: 64 rows x 64B
  const bf16* wsrc0 = wpTb + (long)wrow * 512 + wq;
  bf16* wdst = &Wb[0][wrow * 40 + wq];

  // prologue: u_i rows (f32), dist table, chunk 0
  for (int idx = t; idx < 1024; idx += 256)
    usl[idx >> 9][idx & 511] = Uf[(long)(i0 + (idx >> 9)) * 512 + (idx & 511)];
  for (int idx = t; idx < 640; idx += 256) dts[idx] = dtabg[idx];
  {
    uint4 a0v = *(const uint4*)asrc0;
    uint4 a1v = *(const uint4*)(asrc0 + 8);
    uint4 wv = *(const uint4*)wsrc0;
    *(uint4*)adst = a0v;
    *(uint4*)(adst + 8) = a1v;
    *(uint4*)wdst = wv;
  }
  __syncthreads();

  f32x16 acc[2][2] = {};
  const int aoff = (wjj * 64 + lh) * 40 + half * 8;    // + mf*32*40 + kl*16
  const int woff = lh * 40 + half * 8;                 // + hf*32*40 + kl*16

  for (int kc = 0; kc < 16; ++kc) {
    const int cur = kc & 1;
    uint4 na0, na1, nw;
    if (kc < 15) {                    // issue next-chunk loads early (T14)
      na0 = *(const uint4*)(asrc0 + (kc + 1) * 32);
      na1 = *(const uint4*)(asrc0 + (kc + 1) * 32 + 8);
      nw = *(const uint4*)(wsrc0 + (kc + 1) * 32);
    }
#pragma unroll
    for (int kl = 0; kl < 2; ++kl) {
      const int ks = kc * 2 + kl;
      bf16x8 af0 = *(const bf16x8*)&Ab[cur][aoff + kl * 16];
      bf16x8 af1 = *(const bf16x8*)&Ab[cur][aoff + 32 * 40 + kl * 16];
      bf16x8 wf0 = *(const bf16x8*)&Wb[cur][woff + kl * 16];
      bf16x8 wf1 = *(const bf16x8*)&Wb[cur][woff + 32 * 40 + kl * 16];
      const float* up = &usl[wii][ks * 16 + half * 8];
      float4 u0 = *(const float4*)up;
      float4 u1 = *(const float4*)(up + 4);
      bf16x8 b0, b1;
#pragma unroll
      for (int e = 0; e < 4; ++e) {
        b0[e] = (bf16)(u0[e] * (float)wf0[e]);
        b0[e + 4] = (bf16)(u1[e] * (float)wf0[e + 4]);
        b1[e] = (bf16)(u0[e] * (float)wf1[e]);
        b1[e + 4] = (bf16)(u1[e] * (float)wf1[e + 4]);
      }
      acc[0][0] = MFMA32(af0, b0, acc[0][0]);
      acc[0][1] = MFMA32(af0, b1, acc[0][1]);
      acc[1][0] = MFMA32(af1, b0, acc[1][0]);
      acc[1][1] = MFMA32(af1, b1, acc[1][1]);
    }
    if (kc < 15) {                    // write-late into the other buffer
      bf16* ad = &Ab[cur ^ 1][arow * 40 + ahalf];
      *(uint4*)ad = na0;
      *(uint4*)(ad + 8) = na1;
      *(uint4*)&Wb[cur ^ 1][wrow * 40 + wq] = nw;
    }
    __syncthreads();
  }

  // epilogue: cs[i][j] = (i==j)?0 : sum_h Wo[h]*relu(prod+left_i+right_j+dist)+bo+ss_i+ss_j
  const int i = i0 + wii;
  const float lpf0 = LR[i * 128 + lh];
  const float lpf1 = LR[i * 128 + 32 + lh];
  const float wof0 = Wo[lh], wof1 = Wo[32 + lh];
  const int sbi = sb[i];
  const float ssi = ss[i];
  const float bo0 = bo[0];
#pragma unroll
  for (int mf = 0; mf < 2; ++mf) {
    float4 out[4];
#pragma unroll
    for (int r = 0; r < 16; ++r) {
      int j = jbase + wjj * 64 + mf * 32 + (r & 3) + 8 * (r >> 2) + 4 * half;
      int dd = sbi - sb[j];
      int ad = dd < 0 ? -dd : dd;
      int bkt = ad < 5 ? ad : (31 - __clz(ad)) + 3;
      bkt = bkt > 9 ? 9 : bkt;
      float v0 = fmaxf(acc[mf][0][r] + lpf0 + LR[j * 128 + 64 + lh] +
                       dts[bkt * 64 + lh], 0.f);
      float v1 = fmaxf(acc[mf][1][r] + lpf1 + LR[j * 128 + 96 + lh] +
                       dts[bkt * 64 + 32 + lh], 0.f);
      float sum = v0 * wof0 + v1 * wof1;
      sum += __shfl_xor(sum, 1);
      sum += __shfl_xor(sum, 2);
      sum += __shfl_xor(sum, 4);
      sum += __shfl_xor(sum, 8);
      sum += __shfl_xor(sum, 16);
      out[r >> 2][r & 3] = (j == i) ? 0.f : (sum + bo0 + ssi + ss[j]);
    }
    if (lh == 0) {
#pragma unroll
      for (int g = 0; g < 4; ++g)
        *(float4*)&cs[(long)i * 512 + jbase + wjj * 64 + mf * 32 + 8 * g + 4 * half] =
            out[g];
    }
  }
}

// ---------------------------------------------------------------- masked softmax rows
__global__ __launch_bounds__(64) void k_softmax(const float* __restrict__ cs,
                                                bf16* __restrict__ p12)
{
  int b = blockIdx.x, kind = b >> 9, i = b & 511, lane = threadIdx.x;
  const float* row = cs + i * 512;
  float v[8];
  float4 x0 = *(const float4*)(row + lane * 8);
  float4 x1 = *(const float4*)(row + lane * 8 + 4);
  v[0] = x0.x; v[1] = x0.y; v[2] = x0.z; v[3] = x0.w;
  v[4] = x1.x; v[5] = x1.y; v[6] = x1.z; v[7] = x1.w;
  bool any = (kind == 0) ? (i > 0) : (i < 511);
  bf16x8 ov;
  if (!any) {
    float u = 1.0f / 512.0f;
#pragma unroll
    for (int e = 0; e < 8; ++e) ov[e] = (bf16)u;
  } else {
    float m = -3.4e38f;
#pragma unroll
    for (int e = 0; e < 8; ++e) {
      int jj = lane * 8 + e;
      bool valid = (kind == 0) ? (jj < i) : (jj > i);
      if (valid) m = fmaxf(m, v[e]);
    }
    m = fmaxf(m, __shfl_xor(m, 1));  m = fmaxf(m, __shfl_xor(m, 2));
    m = fmaxf(m, __shfl_xor(m, 4));  m = fmaxf(m, __shfl_xor(m, 8));
    m = fmaxf(m, __shfl_xor(m, 16)); m = fmaxf(m, __shfl_xor(m, 32));
    float p[8]; float ssum = 0.f;
#pragma unroll
    for (int e = 0; e < 8; ++e) {
      int jj = lane * 8 + e;
      bool valid = (kind == 0) ? (jj < i) : (jj > i);
      p[e] = valid ? __expf(v[e] - m) : 0.f;
      ssum += p[e];
    }
    ssum += __shfl_xor(ssum, 1);  ssum += __shfl_xor(ssum, 2);
    ssum += __shfl_xor(ssum, 4);  ssum += __shfl_xor(ssum, 8);
    ssum += __shfl_xor(ssum, 16); ssum += __shfl_xor(ssum, 32);
    float inv = 1.0f / ssum;
#pragma unroll
    for (int e = 0; e < 8; ++e) ov[e] = (bf16)(p[e] * inv);
  }
  *(bf16x8*)(p12 + (long)b * 512 + lane * 8) = ov;
}

// ---------------------------------------------------------------- gate input build
__global__ void k_gatein(const float* __restrict__ c12, bf16* __restrict__ ugb)
{
  for (int idx = blockIdx.x * 256 + threadIdx.x; idx < 262144; idx += 512 * 256) {
    int i = idx >> 9, d = idx & 511;
    ugb[(long)i * 1024 + 512 + d] = (bf16)c12[idx];
    ugb[524288 + (long)i * 1024 + 512 + d] = (bf16)c12[262144 + idx];
  }
}

// ---------------------------------------------------------------- gates + update
__global__ void k_gate(const float* __restrict__ sv, const float* __restrict__ c12,
                       const float* __restrict__ G12, float* __restrict__ upd,
                       bf16* __restrict__ u2)
{
  for (int idx = blockIdx.x * 256 + threadIdx.x; idx < 262144; idx += 512 * 256) {
    float u = sv[idx], c1 = c12[idx], c2 = c12[262144 + idx];
    float g1 = 1.f / (1.f + __expf(-G12[idx]));
    float g2 = 1.f / (1.f + __expf(-G12[262144 + idx]));
    float up = g1 * u + (1.f - g1) * c1 + g2 * u + (1.f - g2) * c2;
    upd[idx] = up;
    u2[idx] = (bf16)up;
  }
}

// ---------------------------------------------------------------- ss2 = update@Wpr + bpr
__global__ __launch_bounds__(64) void k_ss2(const float* __restrict__ upd,
                                            const float* __restrict__ Wpr,
                                            const float* __restrict__ bpr,
                                            float* __restrict__ ss2)
{
  int row = blockIdx.x, lane = threadIdx.x;
  const float* rp = upd + row * 512 + lane * 8;
  const float* wp = Wpr + lane * 8;
  float4 a0 = *(const float4*)rp, a1 = *(const float4*)(rp + 4);
  float4 b0 = *(const float4*)wp, b1 = *(const float4*)(wp + 4);
  float s = a0.x * b0.x + a0.y * b0.y + a0.z * b0.z + a0.w * b0.w +
            a1.x * b1.x + a1.y * b1.y + a1.z * b1.z + a1.w * b1.w;
  s += __shfl_xor(s, 1);  s += __shfl_xor(s, 2);  s += __shfl_xor(s, 4);
  s += __shfl_xor(s, 8);  s += __shfl_xor(s, 16); s += __shfl_xor(s, 32);
  if (lane == 0) ss2[row] = s + bpr[0];
}

// ---------------------------------------------------------------- all_out assembly
__global__ void k_copy(const float* __restrict__ in, float* __restrict__ out)
{
  const float4* i4 = (const float4*)in;
  float4* o4 = (float4*)out;
  for (int idx = blockIdx.x * 256 + threadIdx.x; idx < 2097152; idx += 2048 * 256)
    o4[idx] = i4[idx];
}

__global__ __launch_bounds__(64) void k_scatter(const float* __restrict__ upd,
                                                const int* __restrict__ pi,
                                                const int* __restrict__ sl,
                                                float* __restrict__ out)
{
  int k = blockIdx.x;
  if (k >= sl[0]) return;
  int dst = pi[k];
  int lane = threadIdx.x;
  const float4* s4 = (const float4*)(upd + k * 512);
  float4* d4 = (float4*)(out + (long)dst * 512);
  d4[lane * 2] = s4[lane * 2];
  d4[lane * 2 + 1] = s4[lane * 2 + 1];
}

// ---------------------------------------------------------------- launch
extern "C" void kernel_launch(void* const* d_in, const int* in_sizes, int n_in,
                              void* d_out, int out_size, void* d_ws, size_t ws_size,
                              hipStream_t stream)
{
  const float* asv = (const float*)d_in[0];
  const float* sv = (const float*)d_in[1];
  const int* sb = (const int*)d_in[2];
  const float* sscore = (const float*)d_in[5];
  const int* pi = (const int*)d_in[6];
  const int* sl = (const int*)d_in[7];
  const float* Wl = (const float*)d_in[9];
  const float* bl = (const float*)d_in[10];
  const float* Wr = (const float*)d_in[11];
  const float* br = (const float*)d_in[12];
  const float* Wp = (const float*)d_in[13];
  const float* de = (const float*)d_in[14];
  const float* Wd = (const float*)d_in[15];
  const float* bd = (const float*)d_in[16];
  const float* Wo = (const float*)d_in[17];
  const float* bo = (const float*)d_in[18];
  const float* Wg1 = (const float*)d_in[19];
  const float* bg1 = (const float*)d_in[20];
  const float* Wg2 = (const float*)d_in[21];
  const float* bg2 = (const float*)d_in[22];
  const float* Wpr = (const float*)d_in[23];
  const float* bpr = (const float*)d_in[24];

  float* out_all = (float*)d_out;
  float* out_upd = out_all + 8388608;   // [512][512] update
  float* out_cs = out_all + 8650752;    // [512][512] cs

  char* w = (char*)d_ws;
  size_t off = 0;
  auto take = [&](size_t bytes) -> void* {
    void* p = w + off;
    off = (off + bytes + 255) & ~(size_t)255;
    return p;
  };
  bf16* u1b = (bf16*)take(524288);
  bf16* u2b = (bf16*)take(524288);
  bf16* wlr = (bf16*)take(131072);
  bf16* wgb = (bf16*)take(2097152);
  float* blbr = (float*)take(512);
  float* bgc = (float*)take(4096);
  float* dtab = (float*)take(2560);
  bf16* wpTb = (bf16*)take(65536);
  float* lr1 = (float*)take(262144);
  float* lr2 = (float*)take(262144);
  float* cs1 = (float*)take(1048576);
  bf16* p12 = (bf16*)take(1048576);
  float* c12 = (float*)take(4194304);
  bf16* ugb = (bf16*)take(2097152);
  float* G12 = (float*)take(2097152);
  float* ss2 = (float*)take(2048);

  k_prep<<<2048, 256, 0, stream>>>(sv, Wl, Wr, Wg1, Wg2, de, Wd, bd, bl, br, bg1, bg2,
                                   Wp, u1b, ugb, wlr, blbr, bgc, wgb, dtab, wpTb);
  // left|right for u
  k_gemm<<<dim3(2, 8, 1), 256, 0, stream>>>(u1b, 512, 0, wlr, 128, 0, lr1, 128, 0,
                                            blbr, 0, 512);
  // cs1 = add_scores(pair_scores(u), span_scores)
  k_pair<<<dim3(256, 4), 256, 0, stream>>>(u1b, sv, wpTb, lr1, dtab, sb, sscore, Wo,
                                           bo, cs1);
  // p1,p2
  k_softmax<<<1024, 64, 0, stream>>>(cs1, p12);
  // c1,c2 = [p1;p2] @ u
  k_gemm<<<dim3(8, 16, 1), 256, 0, stream>>>(p12, 512, 0, u1b, 512, 0, c12, 512, 0,
                                             nullptr, 0, 512);
  k_gatein<<<512, 256, 0, stream>>>(c12, ugb);
  // G1,G2 = [u|c] @ Wg + bg   (batched z=2, K=1024)
  k_gemm<<<dim3(8, 8, 2), 256, 0, stream>>>(ugb, 1024, 524288, wgb, 512, 524288,
                                            G12, 512, 262144, bgc, 512, 1024);
  k_gate<<<512, 256, 0, stream>>>(sv, c12, G12, out_upd, u2b);
  k_ss2<<<512, 64, 0, stream>>>(out_upd, Wpr, bpr, ss2);
  // left|right for update
  k_gemm<<<dim3(2, 8, 1), 256, 0, stream>>>(u2b, 512, 0, wlr, 128, 0, lr2, 128, 0,
                                            blbr, 0, 512);
  // cs = add_scores(pair_scores(update), update@Wpr+bpr)
  k_pair<<<dim3(256, 4), 256, 0, stream>>>(u2b, out_upd, wpTb, lr2, dtab, sb, ss2, Wo,
                                           bo, out_cs);
  // all_out
  k_copy<<<2048, 256, 0, stream>>>(asv, out_all);
  k_scatter<<<512, 64, 0, stream>>>(out_upd, pi, sl, out_all);
}

// Round 4
// 181.192 us; speedup vs baseline: 1.1049x; 1.0066x over previous
//
#include <hip/hip_runtime.h>
#include <hip/hip_bf16.h>

// ModuleCorefProp2: coref propagation, B=1, K=512, N=16384, D=512, H=64, NB=10, 1 iter.
// R4: k_pair = one WG per i (512 WGs, 8 waves, all 512 j). Scaled panel V_i = u_i*Wp^T
// built ONCE per i into LDS (was 8x redundant per-wave VALU build). A = U staged via
// global_load_lds w/ XOR-swizzled source; swizzled reads -> conflict-free b128 pattern.

typedef __bf16 bf16;
typedef bf16 bf16x8 __attribute__((ext_vector_type(8)));
typedef float f32x4 __attribute__((ext_vector_type(4)));
typedef float f32x16 __attribute__((ext_vector_type(16)));

#define MFMA16(a, b, c) __builtin_amdgcn_mfma_f32_16x16x32_bf16((a), (b), (c), 0, 0, 0)
#define MFMA32(a, b, c) __builtin_amdgcn_mfma_f32_32x32x16_bf16((a), (b), (c), 0, 0, 0)

__device__ __forceinline__ void gll16(const bf16* g, bf16* lds) {
  __builtin_amdgcn_global_load_lds(
      (const __attribute__((address_space(1))) unsigned int*)g,
      (__attribute__((address_space(3))) unsigned int*)lds, 16, 0, 0);
}

// ---------------------------------------------------------------- prep
__global__ void k_prep(const float* __restrict__ sv,
                       const float* __restrict__ Wl, const float* __restrict__ Wr,
                       const float* __restrict__ Wg1, const float* __restrict__ Wg2,
                       const float* __restrict__ de, const float* __restrict__ Wd,
                       const float* __restrict__ bd, const float* __restrict__ bl,
                       const float* __restrict__ br, const float* __restrict__ bg1,
                       const float* __restrict__ bg2, const float* __restrict__ Wp,
                       bf16* __restrict__ u1, bf16* __restrict__ ugb,
                       bf16* __restrict__ wlr, float* __restrict__ blbr,
                       float* __restrict__ bgc, bf16* __restrict__ wgb,
                       float* __restrict__ dtab, bf16* __restrict__ wpTb)
{
  const int total = 262144 + 65536 + 128 + 1048576 + 1024 + 640 + 32768;
  for (int idx0 = blockIdx.x * 256 + threadIdx.x; idx0 < total; idx0 += 2048 * 256) {
    int k = idx0;
    if (k < 262144) {                 // u -> bf16, and left halves of gate inputs
      float v = sv[k]; bf16 b = (bf16)v; u1[k] = b;
      int i = k >> 9, d = k & 511;
      ugb[(long)i * 1024 + d] = b;
      ugb[524288 + (long)i * 1024 + d] = b;
      continue;
    }
    k -= 262144;
    if (k < 65536) {                  // Wlr = [Wl | Wr] bf16 [512][128]
      int d = k >> 7, h = k & 127;
      wlr[k] = (bf16)(h < 64 ? Wl[d * 64 + h] : Wr[d * 64 + h - 64]);
      continue;
    }
    k -= 65536;
    if (k < 128) { blbr[k] = (k < 64 ? bl[k] : br[k - 64]); continue; }
    k -= 128;
    if (k < 1048576) {                // Wg1|Wg2 bf16 [2][1024][512]
      wgb[k] = (bf16)(k < 524288 ? Wg1[k] : Wg2[k - 524288]);
      continue;
    }
    k -= 1048576;
    if (k < 1024) { bgc[k] = (k < 512 ? bg1[k] : bg2[k - 512]); continue; }
    k -= 1024;
    if (k < 640) {                    // dtab[NB][64] = dist_emb@Wd + bd
      int b_ = k >> 6, h = k & 63;
      float s = bd[h];
      for (int e = 0; e < 64; ++e) s += de[b_ * 64 + e] * Wd[e * 64 + h];
      dtab[k] = s;
      continue;
    }
    k -= 640;
    {                                 // wpTb[h][d] = Wp[d][h], bf16 [64][512]
      int h = k >> 9, d = k & 511;
      wpTb[k] = (bf16)Wp[d * 64 + h];
    }
  }
}

// ---------------------------------------------------------------- generic GEMM
// C[M,N] = A[M,K](bf16) @ B[K,N](bf16) (+bias), 64x64 tiles, 4 waves of 32x32.
__global__ __launch_bounds__(256, 2) void k_gemm(
    const bf16* __restrict__ A, int lda, long asz,
    const bf16* __restrict__ B, int ldb, long bsz,
    float* __restrict__ C, int ldc, long csz,
    const float* __restrict__ bias, int bstride, int K)
{
  __shared__ bf16 As[64 * 40];
  __shared__ bf16 Bs[64 * 40];
  const int t = threadIdx.x, lane = t & 63, wave = t >> 6;
  const int tc = blockIdx.x, tr = blockIdx.y, z = blockIdx.z;
  A += (long)z * asz; B += (long)z * bsz; C += (long)z * csz;
  const int wr = wave >> 1, wc = wave & 1;
  const int arow = t >> 2, aslot = t & 3;
  const int s = lane >> 4, rr = lane & 15;
  f32x4 acc00 = {}, acc01 = {}, acc10 = {}, acc11 = {};
  const int nk = K >> 5;
  for (int kk = 0; kk < nk; ++kk) {
    __syncthreads();
    *(uint4*)&As[arow * 40 + aslot * 8] =
        *(const uint4*)(A + (long)(tr * 64 + arow) * lda + kk * 32 + aslot * 8);
    {
      const bf16* bsrc = B + (long)(kk * 32 + aslot * 8) * ldb + tc * 64 + arow;
      bf16x8 tv;
#pragma unroll
      for (int e = 0; e < 8; ++e) tv[e] = bsrc[(long)e * ldb];
      *(bf16x8*)&Bs[arow * 40 + aslot * 8] = tv;
    }
    __syncthreads();
    bf16x8 a0 = *(const bf16x8*)&As[(wr * 32 + rr) * 40 + s * 8];
    bf16x8 a1 = *(const bf16x8*)&As[(wr * 32 + 16 + rr) * 40 + s * 8];
    bf16x8 b0 = *(const bf16x8*)&Bs[(wc * 32 + rr) * 40 + s * 8];
    bf16x8 b1 = *(const bf16x8*)&Bs[(wc * 32 + 16 + rr) * 40 + s * 8];
    acc00 = MFMA16(a0, b0, acc00);
    acc01 = MFMA16(a0, b1, acc01);
    acc10 = MFMA16(a1, b0, acc10);
    acc11 = MFMA16(a1, b1, acc11);
  }
#pragma unroll
  for (int mf = 0; mf < 2; ++mf) {
#pragma unroll
    for (int nf = 0; nf < 2; ++nf) {
      f32x4 v = mf == 0 ? (nf == 0 ? acc00 : acc01) : (nf == 0 ? acc10 : acc11);
      int col = tc * 64 + wc * 32 + nf * 16 + rr;
      float bi = bias ? bias[z * bstride + col] : 0.f;
      int row0 = tr * 64 + wr * 32 + mf * 16 + s * 4;
#pragma unroll
      for (int r = 0; r < 4; ++r)
        C[(long)(row0 + r) * ldc + col] = v[r] + bi;
    }
  }
}

// ---------------------------------------------------------------- fused pair scorer (R4)
// One WG per i. 512 thr = 8 waves; wave w owns j in [w*64, w*64+64).
// GEMM per WG: prod[j][h] = sum_d U[j,d] * (u_i[d]*WpT[h,d]); M=512(j), N=64(h), K=512(d).
// LDS: As[512][32] bf16 (XOR-swizzled 16B slots), Vs[64][32] bf16 (same swizzle),
// uil[512] f32 (u_i row), dts[640]. Single-buffered 32-d chunks, 2 barriers/chunk.
__global__ __launch_bounds__(512, 4) void k_pair(
    const bf16* __restrict__ Ubf, const float* __restrict__ Uf,
    const bf16* __restrict__ wpTb, const float* __restrict__ LR,
    const float* __restrict__ dtabg, const int* __restrict__ sb,
    const float* __restrict__ ss, const float* __restrict__ Wo,
    const float* __restrict__ bo, float* __restrict__ cs)
{
  __shared__ bf16 As[512 * 32];     // 32KB, row = 64B = 4 x 16B slots
  __shared__ bf16 Vs[64 * 32];      // 4KB
  __shared__ float uil[512];
  __shared__ float dts[640];

  const int t = threadIdx.x;
  const int l = t & 63;
  const int w = t >> 6;
  const int i = blockIdx.x;
  const int half = l >> 5;
  const int l31 = l & 31;

  // ---- prologue: u_i row (f32) + dist table
  if (t < 128) {
    float4 v = *(const float4*)(Uf + (long)i * 512 + t * 4);
    *(float4*)&uil[t * 4] = v;
  }
  for (int idx = t; idx < 640; idx += 512) dts[idx] = dtabg[idx];

  // A-staging source precompute: round q, lds byte = q*8192 + t*16
  // -> row r = q*128 + (t>>2), slot c = t&3, source col slot c' = c ^ ((r>>1)&3)
  const bf16* asrc0;
  const bf16* asrc1;
  const bf16* asrc2;
  const bf16* asrc3;
  {
    int rq0 = 0 * 128 + (t >> 2), rq1 = 1 * 128 + (t >> 2);
    int rq2 = 2 * 128 + (t >> 2), rq3 = 3 * 128 + (t >> 2);
    asrc0 = Ubf + (long)rq0 * 512 + (((t & 3) ^ ((rq0 >> 1) & 3)) * 8);
    asrc1 = Ubf + (long)rq1 * 512 + (((t & 3) ^ ((rq1 >> 1) & 3)) * 8);
    asrc2 = Ubf + (long)rq2 * 512 + (((t & 3) ^ ((rq2 >> 1) & 3)) * 8);
    asrc3 = Ubf + (long)rq3 * 512 + (((t & 3) ^ ((rq3 >> 1) & 3)) * 8);
  }
  // fragment read byte-offsets (constant across chunks; swizzle matches source perm)
  int aoff[2][2], voff[2][2];
#pragma unroll
  for (int jf = 0; jf < 2; ++jf)
#pragma unroll
    for (int ks = 0; ks < 2; ++ks) {
      int r = w * 64 + jf * 32 + l31;
      aoff[jf][ks] = r * 64 + (((ks * 2 + half) ^ ((r >> 1) & 3)) * 16);
    }
#pragma unroll
  for (int hf = 0; hf < 2; ++hf)
#pragma unroll
    for (int ks = 0; ks < 2; ++ks) {
      int h = hf * 32 + l31;
      voff[hf][ks] = h * 64 + (((ks * 2 + half) ^ ((h >> 1) & 3)) * 16);
    }
  // V staging indices (threads 0..255): h = t>>2, slot c = t&3
  const int vh = t >> 2;
  const int vcp = (t & 3) ^ ((vh >> 1) & 3);

  __syncthreads();   // uil visible before first V build

  f32x16 acc[2][2] = {};
  const char* Asb = (const char*)As;
  const char* Vsb = (const char*)Vs;

  for (int kc = 0; kc < 16; ++kc) {
    // stage A chunk (32KB) via global_load_lds, linear dest, swizzled source
    gll16(asrc0 + kc * 32, As + 0 * 4096 + w * 512);
    gll16(asrc1 + kc * 32, As + 1 * 4096 + w * 512);
    gll16(asrc2 + kc * 32, As + 2 * 4096 + w * 512);
    gll16(asrc3 + kc * 32, As + 3 * 4096 + w * 512);
    // stage V chunk (4KB): Vs[h][c] = u_i[.] * WpT[h][.] at source slot c'
    if (t < 256) {
      bf16x8 wv = *(const bf16x8*)(wpTb + (long)vh * 512 + kc * 32 + vcp * 8);
      float4 u0 = *(const float4*)&uil[kc * 32 + vcp * 8];
      float4 u1 = *(const float4*)&uil[kc * 32 + vcp * 8 + 4];
      bf16x8 sv8;
#pragma unroll
      for (int e = 0; e < 4; ++e) {
        sv8[e] = (bf16)((float)wv[e] * u0[e]);
        sv8[e + 4] = (bf16)((float)wv[e + 4] * u1[e]);
      }
      *(bf16x8*)((char*)Vs + vh * 64 + (t & 3) * 16) = sv8;
    }
    asm volatile("s_waitcnt vmcnt(0)");
    __syncthreads();
    // compute: 2 k-slices of 16
#pragma unroll
    for (int ks = 0; ks < 2; ++ks) {
      bf16x8 af0 = *(const bf16x8*)(Asb + aoff[0][ks]);
      bf16x8 af1 = *(const bf16x8*)(Asb + aoff[1][ks]);
      bf16x8 vf0 = *(const bf16x8*)(Vsb + voff[0][ks]);
      bf16x8 vf1 = *(const bf16x8*)(Vsb + voff[1][ks]);
      acc[0][0] = MFMA32(af0, vf0, acc[0][0]);
      acc[0][1] = MFMA32(af0, vf1, acc[0][1]);
      acc[1][0] = MFMA32(af1, vf0, acc[1][0]);
      acc[1][1] = MFMA32(af1, vf1, acc[1][1]);
    }
    __syncthreads();
  }

  // ---- epilogue: cs[i][j] = (i==j)?0 : sum_h Wo[h]*relu(prod+left_i+right_j+dist)+bo+ss_i+ss_j
  const float lf0 = LR[i * 128 + l31];
  const float lf1 = LR[i * 128 + 32 + l31];
  const float wo0 = Wo[l31], wo1 = Wo[32 + l31];
  const int sbi = sb[i];
  const float ssi = ss[i];
  const float bo0 = bo[0];
#pragma unroll
  for (int jf = 0; jf < 2; ++jf) {
#pragma unroll
    for (int r = 0; r < 16; ++r) {
      int j = w * 64 + jf * 32 + (r & 3) + 8 * (r >> 2) + 4 * half;
      int dd = sbi - sb[j];
      int ad = dd < 0 ? -dd : dd;
      int bkt = ad < 5 ? ad : (31 - __clz(ad)) + 3;
      bkt = bkt > 9 ? 9 : bkt;
      float v0 = fmaxf(acc[jf][0][r] + lf0 + LR[j * 128 + 64 + l31] +
                       dts[bkt * 64 + l31], 0.f);
      float v1 = fmaxf(acc[jf][1][r] + lf1 + LR[j * 128 + 96 + l31] +
                       dts[bkt * 64 + 32 + l31], 0.f);
      float sum = v0 * wo0 + v1 * wo1;
      sum += __shfl_xor(sum, 1);
      sum += __shfl_xor(sum, 2);
      sum += __shfl_xor(sum, 4);
      sum += __shfl_xor(sum, 8);
      sum += __shfl_xor(sum, 16);
      if (l31 == 0)
        cs[(long)i * 512 + j] = (j == i) ? 0.f : (sum + bo0 + ssi + ss[j]);
    }
  }
}

// ---------------------------------------------------------------- masked softmax rows
__global__ __launch_bounds__(64) void k_softmax(const float* __restrict__ cs,
                                                bf16* __restrict__ p12)
{
  int b = blockIdx.x, kind = b >> 9, i = b & 511, lane = threadIdx.x;
  const float* row = cs + i * 512;
  float v[8];
  float4 x0 = *(const float4*)(row + lane * 8);
  float4 x1 = *(const float4*)(row + lane * 8 + 4);
  v[0] = x0.x; v[1] = x0.y; v[2] = x0.z; v[3] = x0.w;
  v[4] = x1.x; v[5] = x1.y; v[6] = x1.z; v[7] = x1.w;
  bool any = (kind == 0) ? (i > 0) : (i < 511);
  bf16x8 ov;
  if (!any) {
    float u = 1.0f / 512.0f;
#pragma unroll
    for (int e = 0; e < 8; ++e) ov[e] = (bf16)u;
  } else {
    float m = -3.4e38f;
#pragma unroll
    for (int e = 0; e < 8; ++e) {
      int jj = lane * 8 + e;
      bool valid = (kind == 0) ? (jj < i) : (jj > i);
      if (valid) m = fmaxf(m, v[e]);
    }
    m = fmaxf(m, __shfl_xor(m, 1));  m = fmaxf(m, __shfl_xor(m, 2));
    m = fmaxf(m, __shfl_xor(m, 4));  m = fmaxf(m, __shfl_xor(m, 8));
    m = fmaxf(m, __shfl_xor(m, 16)); m = fmaxf(m, __shfl_xor(m, 32));
    float p[8]; float ssum = 0.f;
#pragma unroll
    for (int e = 0; e < 8; ++e) {
      int jj = lane * 8 + e;
      bool valid = (kind == 0) ? (jj < i) : (jj > i);
      p[e] = valid ? __expf(v[e] - m) : 0.f;
      ssum += p[e];
    }
    ssum += __shfl_xor(ssum, 1);  ssum += __shfl_xor(ssum, 2);
    ssum += __shfl_xor(ssum, 4);  ssum += __shfl_xor(ssum, 8);
    ssum += __shfl_xor(ssum, 16); ssum += __shfl_xor(ssum, 32);
    float inv = 1.0f / ssum;
#pragma unroll
    for (int e = 0; e < 8; ++e) ov[e] = (bf16)(p[e] * inv);
  }
  *(bf16x8*)(p12 + (long)b * 512 + lane * 8) = ov;
}

// ---------------------------------------------------------------- gate input build
__global__ void k_gatein(const float* __restrict__ c12, bf16* __restrict__ ugb)
{
  for (int idx = blockIdx.x * 256 + threadIdx.x; idx < 262144; idx += 512 * 256) {
    int i = idx >> 9, d = idx & 511;
    ugb[(long)i * 1024 + 512 + d] = (bf16)c12[idx];
    ugb[524288 + (long)i * 1024 + 512 + d] = (bf16)c12[262144 + idx];
  }
}

// ---------------------------------------------------------------- gates + update
__global__ void k_gate(const float* __restrict__ sv, const float* __restrict__ c12,
                       const float* __restrict__ G12, float* __restrict__ upd,
                       bf16* __restrict__ u2)
{
  for (int idx = blockIdx.x * 256 + threadIdx.x; idx < 262144; idx += 512 * 256) {
    float u = sv[idx], c1 = c12[idx], c2 = c12[262144 + idx];
    float g1 = 1.f / (1.f + __expf(-G12[idx]));
    float g2 = 1.f / (1.f + __expf(-G12[262144 + idx]));
    float up = g1 * u + (1.f - g1) * c1 + g2 * u + (1.f - g2) * c2;
    upd[idx] = up;
    u2[idx] = (bf16)up;
  }
}

// ---------------------------------------------------------------- ss2 = update@Wpr + bpr
__global__ __launch_bounds__(64) void k_ss2(const float* __restrict__ upd,
                                            const float* __restrict__ Wpr,
                                            const float* __restrict__ bpr,
                                            float* __restrict__ ss2)
{
  int row = blockIdx.x, lane = threadIdx.x;
  const float* rp = upd + row * 512 + lane * 8;
  const float* wp = Wpr + lane * 8;
  float4 a0 = *(const float4*)rp, a1 = *(const float4*)(rp + 4);
  float4 b0 = *(const float4*)wp, b1 = *(const float4*)(wp + 4);
  float s = a0.x * b0.x + a0.y * b0.y + a0.z * b0.z + a0.w * b0.w +
            a1.x * b1.x + a1.y * b1.y + a1.z * b1.z + a1.w * b1.w;
  s += __shfl_xor(s, 1);  s += __shfl_xor(s, 2);  s += __shfl_xor(s, 4);
  s += __shfl_xor(s, 8);  s += __shfl_xor(s, 16); s += __shfl_xor(s, 32);
  if (lane == 0) ss2[row] = s + bpr[0];
}

// ---------------------------------------------------------------- all_out assembly
__global__ void k_copy(const float* __restrict__ in, float* __restrict__ out)
{
  const float4* i4 = (const float4*)in;
  float4* o4 = (float4*)out;
  for (int idx = blockIdx.x * 256 + threadIdx.x; idx < 2097152; idx += 2048 * 256)
    o4[idx] = i4[idx];
}

__global__ __launch_bounds__(64) void k_scatter(const float* __restrict__ upd,
                                                const int* __restrict__ pi,
                                                const int* __restrict__ sl,
                                                float* __restrict__ out)
{
  int k = blockIdx.x;
  if (k >= sl[0]) return;
  int dst = pi[k];
  int lane = threadIdx.x;
  const float4* s4 = (const float4*)(upd + k * 512);
  float4* d4 = (float4*)(out + (long)dst * 512);
  d4[lane * 2] = s4[lane * 2];
  d4[lane * 2 + 1] = s4[lane * 2 + 1];
}

// ---------------------------------------------------------------- launch
extern "C" void kernel_launch(void* const* d_in, const int* in_sizes, int n_in,
                              void* d_out, int out_size, void* d_ws, size_t ws_size,
                              hipStream_t stream)
{
  const float* asv = (const float*)d_in[0];
  const float* sv = (const float*)d_in[1];
  const int* sb = (const int*)d_in[2];
  const float* sscore = (const float*)d_in[5];
  const int* pi = (const int*)d_in[6];
  const int* sl = (const int*)d_in[7];
  const float* Wl = (const float*)d_in[9];
  const float* bl = (const float*)d_in[10];
  const float* Wr = (const float*)d_in[11];
  const float* br = (const float*)d_in[12];
  const float* Wp = (const float*)d_in[13];
  const float* de = (const float*)d_in[14];
  const float* Wd = (const float*)d_in[15];
  const float* bd = (const float*)d_in[16];
  const float* Wo = (const float*)d_in[17];
  const float* bo = (const float*)d_in[18];
  const float* Wg1 = (const float*)d_in[19];
  const float* bg1 = (const float*)d_in[20];
  const float* Wg2 = (const float*)d_in[21];
  const float* bg2 = (const float*)d_in[22];
  const float* Wpr = (const float*)d_in[23];
  const float* bpr = (const float*)d_in[24];

  float* out_all = (float*)d_out;
  float* out_upd = out_all + 8388608;   // [512][512] update
  float* out_cs = out_all + 8650752;    // [512][512] cs

  char* w = (char*)d_ws;
  size_t off = 0;
  auto take = [&](size_t bytes) -> void* {
    void* p = w + off;
    off = (off + bytes + 255) & ~(size_t)255;
    return p;
  };
  bf16* u1b = (bf16*)take(524288);
  bf16* u2b = (bf16*)take(524288);
  bf16* wlr = (bf16*)take(131072);
  bf16* wgb = (bf16*)take(2097152);
  float* blbr = (float*)take(512);
  float* bgc = (float*)take(4096);
  float* dtab = (float*)take(2560);
  bf16* wpTb = (bf16*)take(65536);
  float* lr1 = (float*)take(262144);
  float* lr2 = (float*)take(262144);
  float* cs1 = (float*)take(1048576);
  bf16* p12 = (bf16*)take(1048576);
  float* c12 = (float*)take(4194304);
  bf16* ugb = (bf16*)take(2097152);
  float* G12 = (float*)take(2097152);
  float* ss2 = (float*)take(2048);

  k_prep<<<2048, 256, 0, stream>>>(sv, Wl, Wr, Wg1, Wg2, de, Wd, bd, bl, br, bg1, bg2,
                                   Wp, u1b, ugb, wlr, blbr, bgc, wgb, dtab, wpTb);
  // left|right for u
  k_gemm<<<dim3(2, 8, 1), 256, 0, stream>>>(u1b, 512, 0, wlr, 128, 0, lr1, 128, 0,
                                            blbr, 0, 512);
  // cs1 = add_scores(pair_scores(u), span_scores)
  k_pair<<<512, 512, 0, stream>>>(u1b, sv, wpTb, lr1, dtab, sb, sscore, Wo, bo, cs1);
  // p1,p2
  k_softmax<<<1024, 64, 0, stream>>>(cs1, p12);
  // c1,c2 = [p1;p2] @ u
  k_gemm<<<dim3(8, 16, 1), 256, 0, stream>>>(p12, 512, 0, u1b, 512, 0, c12, 512, 0,
                                             nullptr, 0, 512);
  k_gatein<<<512, 256, 0, stream>>>(c12, ugb);
  // G1,G2 = [u|c] @ Wg + bg   (batched z=2, K=1024)
  k_gemm<<<dim3(8, 8, 2), 256, 0, stream>>>(ugb, 1024, 524288, wgb, 512, 524288,
                                            G12, 512, 262144, bgc, 512, 1024);
  k_gate<<<512, 256, 0, stream>>>(sv, c12, G12, out_upd, u2b);
  k_ss2<<<512, 64, 0, stream>>>(out_upd, Wpr, bpr, ss2);
  // left|right for update
  k_gemm<<<dim3(2, 8, 1), 256, 0, stream>>>(u2b, 512, 0, wlr, 128, 0, lr2, 128, 0,
                                            blbr, 0, 512);
  // cs = add_scores(pair_scores(update), update@Wpr+bpr)
  k_pair<<<512, 512, 0, stream>>>(u2b, out_upd, wpTb, lr2, dtab, sb, ss2, Wo, bo,
                                  out_cs);
  // all_out
  k_copy<<<2048, 256, 0, stream>>>(asv, out_all);
  k_scatter<<<512, 64, 0, stream>>>(out_upd, pi, sl, out_all);
}

// Round 5
// 179.886 us; speedup vs baseline: 1.1129x; 1.0073x over previous
//
#include <hip/hip_runtime.h>
#include <hip/hip_bf16.h>

// ModuleCorefProp2: coref propagation, B=1, K=512, N=16384, D=512, H=64, NB=10, 1 iter.
// R5: k_pair gets T3-style pipelining: double-buffered A/V chunks, stage(k+1) issued
// BEFORE compute(k), counted drain (vmcnt(0) only after compute), ONE barrier/chunk,
// s_setprio around MFMA cluster. k_ss2 fused into k_gate.

typedef __bf16 bf16;
typedef bf16 bf16x8 __attribute__((ext_vector_type(8)));
typedef float f32x4 __attribute__((ext_vector_type(4)));
typedef float f32x16 __attribute__((ext_vector_type(16)));

#define MFMA16(a, b, c) __builtin_amdgcn_mfma_f32_16x16x32_bf16((a), (b), (c), 0, 0, 0)
#define MFMA32(a, b, c) __builtin_amdgcn_mfma_f32_32x32x16_bf16((a), (b), (c), 0, 0, 0)

__device__ __forceinline__ void gll16(const bf16* g, bf16* lds) {
  __builtin_amdgcn_global_load_lds(
      (const __attribute__((address_space(1))) unsigned int*)g,
      (__attribute__((address_space(3))) unsigned int*)lds, 16, 0, 0);
}

// ---------------------------------------------------------------- prep
__global__ void k_prep(const float* __restrict__ sv,
                       const float* __restrict__ Wl, const float* __restrict__ Wr,
                       const float* __restrict__ Wg1, const float* __restrict__ Wg2,
                       const float* __restrict__ de, const float* __restrict__ Wd,
                       const float* __restrict__ bd, const float* __restrict__ bl,
                       const float* __restrict__ br, const float* __restrict__ bg1,
                       const float* __restrict__ bg2, const float* __restrict__ Wp,
                       bf16* __restrict__ u1, bf16* __restrict__ ugb,
                       bf16* __restrict__ wlr, float* __restrict__ blbr,
                       float* __restrict__ bgc, bf16* __restrict__ wgb,
                       float* __restrict__ dtab, bf16* __restrict__ wpTb)
{
  const int total = 262144 + 65536 + 128 + 1048576 + 1024 + 640 + 32768;
  for (int idx0 = blockIdx.x * 256 + threadIdx.x; idx0 < total; idx0 += 2048 * 256) {
    int k = idx0;
    if (k < 262144) {                 // u -> bf16, and left halves of gate inputs
      float v = sv[k]; bf16 b = (bf16)v; u1[k] = b;
      int i = k >> 9, d = k & 511;
      ugb[(long)i * 1024 + d] = b;
      ugb[524288 + (long)i * 1024 + d] = b;
      continue;
    }
    k -= 262144;
    if (k < 65536) {                  // Wlr = [Wl | Wr] bf16 [512][128]
      int d = k >> 7, h = k & 127;
      wlr[k] = (bf16)(h < 64 ? Wl[d * 64 + h] : Wr[d * 64 + h - 64]);
      continue;
    }
    k -= 65536;
    if (k < 128) { blbr[k] = (k < 64 ? bl[k] : br[k - 64]); continue; }
    k -= 128;
    if (k < 1048576) {                // Wg1|Wg2 bf16 [2][1024][512]
      wgb[k] = (bf16)(k < 524288 ? Wg1[k] : Wg2[k - 524288]);
      continue;
    }
    k -= 1048576;
    if (k < 1024) { bgc[k] = (k < 512 ? bg1[k] : bg2[k - 512]); continue; }
    k -= 1024;
    if (k < 640) {                    // dtab[NB][64] = dist_emb@Wd + bd
      int b_ = k >> 6, h = k & 63;
      float s = bd[h];
      for (int e = 0; e < 64; ++e) s += de[b_ * 64 + e] * Wd[e * 64 + h];
      dtab[k] = s;
      continue;
    }
    k -= 640;
    {                                 // wpTb[h][d] = Wp[d][h], bf16 [64][512]
      int h = k >> 9, d = k & 511;
      wpTb[k] = (bf16)Wp[d * 64 + h];
    }
  }
}

// ---------------------------------------------------------------- generic GEMM
// C[M,N] = A[M,K](bf16) @ B[K,N](bf16) (+bias), 64x64 tiles, 4 waves of 32x32.
__global__ __launch_bounds__(256, 2) void k_gemm(
    const bf16* __restrict__ A, int lda, long asz,
    const bf16* __restrict__ B, int ldb, long bsz,
    float* __restrict__ C, int ldc, long csz,
    const float* __restrict__ bias, int bstride, int K)
{
  __shared__ bf16 As[64 * 40];
  __shared__ bf16 Bs[64 * 40];
  const int t = threadIdx.x, lane = t & 63, wave = t >> 6;
  const int tc = blockIdx.x, tr = blockIdx.y, z = blockIdx.z;
  A += (long)z * asz; B += (long)z * bsz; C += (long)z * csz;
  const int wr = wave >> 1, wc = wave & 1;
  const int arow = t >> 2, aslot = t & 3;
  const int s = lane >> 4, rr = lane & 15;
  f32x4 acc00 = {}, acc01 = {}, acc10 = {}, acc11 = {};
  const int nk = K >> 5;
  for (int kk = 0; kk < nk; ++kk) {
    __syncthreads();
    *(uint4*)&As[arow * 40 + aslot * 8] =
        *(const uint4*)(A + (long)(tr * 64 + arow) * lda + kk * 32 + aslot * 8);
    {
      const bf16* bsrc = B + (long)(kk * 32 + aslot * 8) * ldb + tc * 64 + arow;
      bf16x8 tv;
#pragma unroll
      for (int e = 0; e < 8; ++e) tv[e] = bsrc[(long)e * ldb];
      *(bf16x8*)&Bs[arow * 40 + aslot * 8] = tv;
    }
    __syncthreads();
    bf16x8 a0 = *(const bf16x8*)&As[(wr * 32 + rr) * 40 + s * 8];
    bf16x8 a1 = *(const bf16x8*)&As[(wr * 32 + 16 + rr) * 40 + s * 8];
    bf16x8 b0 = *(const bf16x8*)&Bs[(wc * 32 + rr) * 40 + s * 8];
    bf16x8 b1 = *(const bf16x8*)&Bs[(wc * 32 + 16 + rr) * 40 + s * 8];
    acc00 = MFMA16(a0, b0, acc00);
    acc01 = MFMA16(a0, b1, acc01);
    acc10 = MFMA16(a1, b0, acc10);
    acc11 = MFMA16(a1, b1, acc11);
  }
#pragma unroll
  for (int mf = 0; mf < 2; ++mf) {
#pragma unroll
    for (int nf = 0; nf < 2; ++nf) {
      f32x4 v = mf == 0 ? (nf == 0 ? acc00 : acc01) : (nf == 0 ? acc10 : acc11);
      int col = tc * 64 + wc * 32 + nf * 16 + rr;
      float bi = bias ? bias[z * bstride + col] : 0.f;
      int row0 = tr * 64 + wr * 32 + mf * 16 + s * 4;
#pragma unroll
      for (int r = 0; r < 4; ++r)
        C[(long)(row0 + r) * ldc + col] = v[r] + bi;
    }
  }
}

// ---------------------------------------------------------------- fused pair scorer (R5)
// One WG per i; 8 waves; wave w owns j in [w*64, w*64+64). Double-buffered 32-d chunks:
// issue stage(k+1) -> compute(k) -> vmcnt(0) -> barrier. One barrier per chunk.
__global__ __launch_bounds__(512, 2) void k_pair(
    const bf16* __restrict__ Ubf, const float* __restrict__ Uf,
    const bf16* __restrict__ wpTb, const float* __restrict__ LR,
    const float* __restrict__ dtabg, const int* __restrict__ sb,
    const float* __restrict__ ss, const float* __restrict__ Wo,
    const float* __restrict__ bo, float* __restrict__ cs)
{
  __shared__ bf16 As[2][512 * 32];  // 2 x 32KB, row = 64B = 4 x 16B slots
  __shared__ bf16 Vs[2][64 * 32];   // 2 x 4KB
  __shared__ float uil[512];
  __shared__ float dts[640];

  const int t = threadIdx.x;
  const int l = t & 63;
  const int w = t >> 6;
  const int i = blockIdx.x;
  const int half = l >> 5;
  const int l31 = l & 31;

  // ---- prologue: u_i row (f32) + dist table
  if (t < 128) {
    float4 v = *(const float4*)(Uf + (long)i * 512 + t * 4);
    *(float4*)&uil[t * 4] = v;
  }
  for (int idx = t; idx < 640; idx += 512) dts[idx] = dtabg[idx];

  // A-staging source: round q, lds byte = q*8192 + t*16
  // -> row r = q*128 + (t>>2), slot c = t&3, source col slot c' = c ^ ((r>>1)&3)
  const bf16 *asrc0, *asrc1, *asrc2, *asrc3;
  {
    int rq0 = 0 * 128 + (t >> 2), rq1 = 1 * 128 + (t >> 2);
    int rq2 = 2 * 128 + (t >> 2), rq3 = 3 * 128 + (t >> 2);
    asrc0 = Ubf + (long)rq0 * 512 + (((t & 3) ^ ((rq0 >> 1) & 3)) * 8);
    asrc1 = Ubf + (long)rq1 * 512 + (((t & 3) ^ ((rq1 >> 1) & 3)) * 8);
    asrc2 = Ubf + (long)rq2 * 512 + (((t & 3) ^ ((rq2 >> 1) & 3)) * 8);
    asrc3 = Ubf + (long)rq3 * 512 + (((t & 3) ^ ((rq3 >> 1) & 3)) * 8);
  }
  // fragment read byte-offsets (swizzle matches source perm)
  int aoff[2][2], voff[2][2];
#pragma unroll
  for (int jf = 0; jf < 2; ++jf)
#pragma unroll
    for (int ks = 0; ks < 2; ++ks) {
      int r = w * 64 + jf * 32 + l31;
      aoff[jf][ks] = r * 64 + (((ks * 2 + half) ^ ((r >> 1) & 3)) * 16);
    }
#pragma unroll
  for (int hf = 0; hf < 2; ++hf)
#pragma unroll
    for (int ks = 0; ks < 2; ++ks) {
      int h = hf * 32 + l31;
      voff[hf][ks] = h * 64 + (((ks * 2 + half) ^ ((h >> 1) & 3)) * 16);
    }
  // V staging indices (threads 0..255): h = t>>2, physical slot t&3, logical slot vcp
  const int vh = t >> 2;
  const int vcp = (t & 3) ^ ((vh >> 1) & 3);

  __syncthreads();   // uil visible before V builds

  // ---- stage chunk 0 into buf 0
  gll16(asrc0, &As[0][0 * 4096 + w * 512]);
  gll16(asrc1, &As[0][1 * 4096 + w * 512]);
  gll16(asrc2, &As[0][2 * 4096 + w * 512]);
  gll16(asrc3, &As[0][3 * 4096 + w * 512]);
  if (t < 256) {
    bf16x8 wv = *(const bf16x8*)(wpTb + (long)vh * 512 + vcp * 8);
    float4 u0 = *(const float4*)&uil[vcp * 8];
    float4 u1 = *(const float4*)&uil[vcp * 8 + 4];
    bf16x8 sv8;
#pragma unroll
    for (int e = 0; e < 4; ++e) {
      sv8[e] = (bf16)((float)wv[e] * u0[e]);
      sv8[e + 4] = (bf16)((float)wv[e + 4] * u1[e]);
    }
    *(bf16x8*)((char*)&Vs[0][0] + vh * 64 + (t & 3) * 16) = sv8;
  }
  asm volatile("s_waitcnt vmcnt(0)");
  __syncthreads();

  f32x16 acc[2][2] = {};

  for (int kc = 0; kc < 16; ++kc) {
    const int cur = kc & 1;
    // issue stage for chunk kc+1 into the other buffer (before compute: T14)
    if (kc < 15) {
      gll16(asrc0 + (kc + 1) * 32, &As[cur ^ 1][0 * 4096 + w * 512]);
      gll16(asrc1 + (kc + 1) * 32, &As[cur ^ 1][1 * 4096 + w * 512]);
      gll16(asrc2 + (kc + 1) * 32, &As[cur ^ 1][2 * 4096 + w * 512]);
      gll16(asrc3 + (kc + 1) * 32, &As[cur ^ 1][3 * 4096 + w * 512]);
      if (t < 256) {
        bf16x8 wv = *(const bf16x8*)(wpTb + (long)vh * 512 + (kc + 1) * 32 + vcp * 8);
        float4 u0 = *(const float4*)&uil[(kc + 1) * 32 + vcp * 8];
        float4 u1 = *(const float4*)&uil[(kc + 1) * 32 + vcp * 8 + 4];
        bf16x8 sv8;
#pragma unroll
        for (int e = 0; e < 4; ++e) {
          sv8[e] = (bf16)((float)wv[e] * u0[e]);
          sv8[e + 4] = (bf16)((float)wv[e + 4] * u1[e]);
        }
        *(bf16x8*)((char*)&Vs[cur ^ 1][0] + vh * 64 + (t & 3) * 16) = sv8;
      }
    }
    // compute chunk kc from buf cur
    const char* Asb = (const char*)&As[cur][0];
    const char* Vsb = (const char*)&Vs[cur][0];
#pragma unroll
    for (int ks = 0; ks < 2; ++ks) {
      bf16x8 af0 = *(const bf16x8*)(Asb + aoff[0][ks]);
      bf16x8 af1 = *(const bf16x8*)(Asb + aoff[1][ks]);
      bf16x8 vf0 = *(const bf16x8*)(Vsb + voff[0][ks]);
      bf16x8 vf1 = *(const bf16x8*)(Vsb + voff[1][ks]);
      __builtin_amdgcn_s_setprio(1);
      acc[0][0] = MFMA32(af0, vf0, acc[0][0]);
      acc[0][1] = MFMA32(af0, vf1, acc[0][1]);
      acc[1][0] = MFMA32(af1, vf0, acc[1][0]);
      acc[1][1] = MFMA32(af1, vf1, acc[1][1]);
      __builtin_amdgcn_s_setprio(0);
    }
    // wait for next-chunk staging, then one barrier
    if (kc < 15) asm volatile("s_waitcnt vmcnt(0)");
    __syncthreads();
  }

  // ---- epilogue: cs[i][j] = (i==j)?0 : sum_h Wo[h]*relu(prod+left_i+right_j+dist)+bo+ss_i+ss_j
  const float lf0 = LR[i * 128 + l31];
  const float lf1 = LR[i * 128 + 32 + l31];
  const float wo0 = Wo[l31], wo1 = Wo[32 + l31];
  const int sbi = sb[i];
  const float ssi = ss[i];
  const float bo0 = bo[0];
#pragma unroll
  for (int jf = 0; jf < 2; ++jf) {
#pragma unroll
    for (int r = 0; r < 16; ++r) {
      int j = w * 64 + jf * 32 + (r & 3) + 8 * (r >> 2) + 4 * half;
      int dd = sbi - sb[j];
      int ad = dd < 0 ? -dd : dd;
      int bkt = ad < 5 ? ad : (31 - __clz(ad)) + 3;
      bkt = bkt > 9 ? 9 : bkt;
      float v0 = fmaxf(acc[jf][0][r] + lf0 + LR[j * 128 + 64 + l31] +
                       dts[bkt * 64 + l31], 0.f);
      float v1 = fmaxf(acc[jf][1][r] + lf1 + LR[j * 128 + 96 + l31] +
                       dts[bkt * 64 + 32 + l31], 0.f);
      float sum = v0 * wo0 + v1 * wo1;
      sum += __shfl_xor(sum, 1);
      sum += __shfl_xor(sum, 2);
      sum += __shfl_xor(sum, 4);
      sum += __shfl_xor(sum, 8);
      sum += __shfl_xor(sum, 16);
      if (l31 == 0)
        cs[(long)i * 512 + j] = (j == i) ? 0.f : (sum + bo0 + ssi + ss[j]);
    }
  }
}

// ---------------------------------------------------------------- masked softmax rows
__global__ __launch_bounds__(64) void k_softmax(const float* __restrict__ cs,
                                                bf16* __restrict__ p12)
{
  int b = blockIdx.x, kind = b >> 9, i = b & 511, lane = threadIdx.x;
  const float* row = cs + i * 512;
  float v[8];
  float4 x0 = *(const float4*)(row + lane * 8);
  float4 x1 = *(const float4*)(row + lane * 8 + 4);
  v[0] = x0.x; v[1] = x0.y; v[2] = x0.z; v[3] = x0.w;
  v[4] = x1.x; v[5] = x1.y; v[6] = x1.z; v[7] = x1.w;
  bool any = (kind == 0) ? (i > 0) : (i < 511);
  bf16x8 ov;
  if (!any) {
    float u = 1.0f / 512.0f;
#pragma unroll
    for (int e = 0; e < 8; ++e) ov[e] = (bf16)u;
  } else {
    float m = -3.4e38f;
#pragma unroll
    for (int e = 0; e < 8; ++e) {
      int jj = lane * 8 + e;
      bool valid = (kind == 0) ? (jj < i) : (jj > i);
      if (valid) m = fmaxf(m, v[e]);
    }
    m = fmaxf(m, __shfl_xor(m, 1));  m = fmaxf(m, __shfl_xor(m, 2));
    m = fmaxf(m, __shfl_xor(m, 4));  m = fmaxf(m, __shfl_xor(m, 8));
    m = fmaxf(m, __shfl_xor(m, 16)); m = fmaxf(m, __shfl_xor(m, 32));
    float p[8]; float ssum = 0.f;
#pragma unroll
    for (int e = 0; e < 8; ++e) {
      int jj = lane * 8 + e;
      bool valid = (kind == 0) ? (jj < i) : (jj > i);
      p[e] = valid ? __expf(v[e] - m) : 0.f;
      ssum += p[e];
    }
    ssum += __shfl_xor(ssum, 1);  ssum += __shfl_xor(ssum, 2);
    ssum += __shfl_xor(ssum, 4);  ssum += __shfl_xor(ssum, 8);
    ssum += __shfl_xor(ssum, 16); ssum += __shfl_xor(ssum, 32);
    float inv = 1.0f / ssum;
#pragma unroll
    for (int e = 0; e < 8; ++e) ov[e] = (bf16)(p[e] * inv);
  }
  *(bf16x8*)(p12 + (long)b * 512 + lane * 8) = ov;
}

// ---------------------------------------------------------------- gate input build
__global__ void k_gatein(const float* __restrict__ c12, bf16* __restrict__ ugb)
{
  for (int idx = blockIdx.x * 256 + threadIdx.x; idx < 262144; idx += 512 * 256) {
    int i = idx >> 9, d = idx & 511;
    ugb[(long)i * 1024 + 512 + d] = (bf16)c12[idx];
    ugb[524288 + (long)i * 1024 + 512 + d] = (bf16)c12[262144 + idx];
  }
}

// ---------------------------------------------------------------- gates + update (+ ss2 fused)
__global__ __launch_bounds__(256) void k_gate(
    const float* __restrict__ sv, const float* __restrict__ c12,
    const float* __restrict__ G12, const float* __restrict__ Wpr,
    const float* __restrict__ bpr, float* __restrict__ upd,
    bf16* __restrict__ u2, float* __restrict__ ss2)
{
  __shared__ float red[4];
  const int row = blockIdx.x;
  const int t = threadIdx.x;
  float dot = 0.f;
#pragma unroll
  for (int hlf = 0; hlf < 2; ++hlf) {
    int ii = row * 512 + hlf * 256 + t;
    float u = sv[ii], c1 = c12[ii], c2 = c12[262144 + ii];
    float g1 = 1.f / (1.f + __expf(-G12[ii]));
    float g2 = 1.f / (1.f + __expf(-G12[262144 + ii]));
    float up = g1 * u + (1.f - g1) * c1 + g2 * u + (1.f - g2) * c2;
    upd[ii] = up;
    u2[ii] = (bf16)up;
    dot += up * Wpr[hlf * 256 + t];
  }
  dot += __shfl_xor(dot, 1);  dot += __shfl_xor(dot, 2);
  dot += __shfl_xor(dot, 4);  dot += __shfl_xor(dot, 8);
  dot += __shfl_xor(dot, 16); dot += __shfl_xor(dot, 32);
  if ((t & 63) == 0) red[t >> 6] = dot;
  __syncthreads();
  if (t == 0) ss2[row] = red[0] + red[1] + red[2] + red[3] + bpr[0];
}

// ---------------------------------------------------------------- all_out assembly
__global__ void k_copy(const float* __restrict__ in, float* __restrict__ out)
{
  const float4* i4 = (const float4*)in;
  float4* o4 = (float4*)out;
  for (int idx = blockIdx.x * 256 + threadIdx.x; idx < 2097152; idx += 2048 * 256)
    o4[idx] = i4[idx];
}

__global__ __launch_bounds__(64) void k_scatter(const float* __restrict__ upd,
                                                const int* __restrict__ pi,
                                                const int* __restrict__ sl,
                                                float* __restrict__ out)
{
  int k = blockIdx.x;
  if (k >= sl[0]) return;
  int dst = pi[k];
  int lane = threadIdx.x;
  const float4* s4 = (const float4*)(upd + k * 512);
  float4* d4 = (float4*)(out + (long)dst * 512);
  d4[lane * 2] = s4[lane * 2];
  d4[lane * 2 + 1] = s4[lane * 2 + 1];
}

// ---------------------------------------------------------------- launch
extern "C" void kernel_launch(void* const* d_in, const int* in_sizes, int n_in,
                              void* d_out, int out_size, void* d_ws, size_t ws_size,
                              hipStream_t stream)
{
  const float* asv = (const float*)d_in[0];
  const float* sv = (const float*)d_in[1];
  const int* sb = (const int*)d_in[2];
  const float* sscore = (const float*)d_in[5];
  const int* pi = (const int*)d_in[6];
  const int* sl = (const int*)d_in[7];
  const float* Wl = (const float*)d_in[9];
  const float* bl = (const float*)d_in[10];
  const float* Wr = (const float*)d_in[11];
  const float* br = (const float*)d_in[12];
  const float* Wp = (const float*)d_in[13];
  const float* de = (const float*)d_in[14];
  const float* Wd = (const float*)d_in[15];
  const float* bd = (const float*)d_in[16];
  const float* Wo = (const float*)d_in[17];
  const float* bo = (const float*)d_in[18];
  const float* Wg1 = (const float*)d_in[19];
  const float* bg1 = (const float*)d_in[20];
  const float* Wg2 = (const float*)d_in[21];
  const float* bg2 = (const float*)d_in[22];
  const float* Wpr = (const float*)d_in[23];
  const float* bpr = (const float*)d_in[24];

  float* out_all = (float*)d_out;
  float* out_upd = out_all + 8388608;   // [512][512] update
  float* out_cs = out_all + 8650752;    // [512][512] cs

  char* w = (char*)d_ws;
  size_t off = 0;
  auto take = [&](size_t bytes) -> void* {
    void* p = w + off;
    off = (off + bytes + 255) & ~(size_t)255;
    return p;
  };
  bf16* u1b = (bf16*)take(524288);
  bf16* u2b = (bf16*)take(524288);
  bf16* wlr = (bf16*)take(131072);
  bf16* wgb = (bf16*)take(2097152);
  float* blbr = (float*)take(512);
  float* bgc = (float*)take(4096);
  float* dtab = (float*)take(2560);
  bf16* wpTb = (bf16*)take(65536);
  float* lr1 = (float*)take(262144);
  float* lr2 = (float*)take(262144);
  float* cs1 = (float*)take(1048576);
  bf16* p12 = (bf16*)take(1048576);
  float* c12 = (float*)take(4194304);
  bf16* ugb = (bf16*)take(2097152);
  float* G12 = (float*)take(2097152);
  float* ss2 = (float*)take(2048);

  k_prep<<<2048, 256, 0, stream>>>(sv, Wl, Wr, Wg1, Wg2, de, Wd, bd, bl, br, bg1, bg2,
                                   Wp, u1b, ugb, wlr, blbr, bgc, wgb, dtab, wpTb);
  // left|right for u
  k_gemm<<<dim3(2, 8, 1), 256, 0, stream>>>(u1b, 512, 0, wlr, 128, 0, lr1, 128, 0,
                                            blbr, 0, 512);
  // cs1 = add_scores(pair_scores(u), span_scores)
  k_pair<<<512, 512, 0, stream>>>(u1b, sv, wpTb, lr1, dtab, sb, sscore, Wo, bo, cs1);
  // p1,p2
  k_softmax<<<1024, 64, 0, stream>>>(cs1, p12);
  // c1,c2 = [p1;p2] @ u
  k_gemm<<<dim3(8, 16, 1), 256, 0, stream>>>(p12, 512, 0, u1b, 512, 0, c12, 512, 0,
                                             nullptr, 0, 512);
  k_gatein<<<512, 256, 0, stream>>>(c12, ugb);
  // G1,G2 = [u|c] @ Wg + bg   (batched z=2, K=1024)
  k_gemm<<<dim3(8, 8, 2), 256, 0, stream>>>(ugb, 1024, 524288, wgb, 512, 524288,
                                            G12, 512, 262144, bgc, 512, 1024);
  // update + u2 bf16 + ss2 (fused)
  k_gate<<<512, 256, 0, stream>>>(sv, c12, G12, Wpr, bpr, out_upd, u2b, ss2);
  // left|right for update
  k_gemm<<<dim3(2, 8, 1), 256, 0, stream>>>(u2b, 512, 0, wlr, 128, 0, lr2, 128, 0,
                                            blbr, 0, 512);
  // cs = add_scores(pair_scores(update), update@Wpr+bpr)
  k_pair<<<512, 512, 0, stream>>>(u2b, out_upd, wpTb, lr2, dtab, sb, ss2, Wo, bo,
                                  out_cs);
  // all_out
  k_copy<<<2048, 256, 0, stream>>>(asv, out_all);
  k_scatter<<<512, 64, 0, stream>>>(out_upd, pi, sl, out_all);
}

// Round 6
// 170.549 us; speedup vs baseline: 1.1738x; 1.0547x over previous
//
#include <hip/hip_runtime.h>
#include <hip/hip_bf16.h>

// ModuleCorefProp2: coref propagation, B=1, K=512, N=16384, D=512, H=64, NB=10, 1 iter.
// R6: dispatch-count and idle-pipe round. k_pair K-loop unchanged (45us control).
//  - all_span_vecs copy folded into k_pair #1 tail (rides idle HBM pipe)
//  - gate + ss2 + lr2 + scatter fused into k_mid2 (row-local)
//  - gatein folded into c12 k_gemm epilogue (bf16 side-write)
//  - 12 -> 8 dispatches

typedef __bf16 bf16;
typedef bf16 bf16x8 __attribute__((ext_vector_type(8)));
typedef float f32x4 __attribute__((ext_vector_type(4)));
typedef float f32x16 __attribute__((ext_vector_type(16)));

#define MFMA16(a, b, c) __builtin_amdgcn_mfma_f32_16x16x32_bf16((a), (b), (c), 0, 0, 0)
#define MFMA32(a, b, c) __builtin_amdgcn_mfma_f32_32x32x16_bf16((a), (b), (c), 0, 0, 0)

__device__ __forceinline__ void gll16(const bf16* g, bf16* lds) {
  __builtin_amdgcn_global_load_lds(
      (const __attribute__((address_space(1))) unsigned int*)g,
      (__attribute__((address_space(3))) unsigned int*)lds, 16, 0, 0);
}

// ---------------------------------------------------------------- prep
__global__ void k_prep(const float* __restrict__ sv,
                       const float* __restrict__ Wl, const float* __restrict__ Wr,
                       const float* __restrict__ Wg1, const float* __restrict__ Wg2,
                       const float* __restrict__ de, const float* __restrict__ Wd,
                       const float* __restrict__ bd, const float* __restrict__ bl,
                       const float* __restrict__ br, const float* __restrict__ bg1,
                       const float* __restrict__ bg2, const float* __restrict__ Wp,
                       bf16* __restrict__ u1, bf16* __restrict__ ugb,
                       bf16* __restrict__ wlr, float* __restrict__ blbr,
                       float* __restrict__ bgc, bf16* __restrict__ wgb,
                       float* __restrict__ dtab, bf16* __restrict__ wpTb)
{
  const int total = 262144 + 65536 + 128 + 1048576 + 1024 + 640 + 32768;
  for (int idx0 = blockIdx.x * 256 + threadIdx.x; idx0 < total; idx0 += 2048 * 256) {
    int k = idx0;
    if (k < 262144) {                 // u -> bf16, and left halves of gate inputs
      float v = sv[k]; bf16 b = (bf16)v; u1[k] = b;
      int i = k >> 9, d = k & 511;
      ugb[(long)i * 1024 + d] = b;
      ugb[524288 + (long)i * 1024 + d] = b;
      continue;
    }
    k -= 262144;
    if (k < 65536) {                  // Wlr = [Wl | Wr] bf16 [512][128]
      int d = k >> 7, h = k & 127;
      wlr[k] = (bf16)(h < 64 ? Wl[d * 64 + h] : Wr[d * 64 + h - 64]);
      continue;
    }
    k -= 65536;
    if (k < 128) { blbr[k] = (k < 64 ? bl[k] : br[k - 64]); continue; }
    k -= 128;
    if (k < 1048576) {                // Wg1|Wg2 bf16 [2][1024][512]
      wgb[k] = (bf16)(k < 524288 ? Wg1[k] : Wg2[k - 524288]);
      continue;
    }
    k -= 1048576;
    if (k < 1024) { bgc[k] = (k < 512 ? bg1[k] : bg2[k - 512]); continue; }
    k -= 1024;
    if (k < 640) {                    // dtab[NB][64] = dist_emb@Wd + bd
      int b_ = k >> 6, h = k & 63;
      float s = bd[h];
      for (int e = 0; e < 64; ++e) s += de[b_ * 64 + e] * Wd[e * 64 + h];
      dtab[k] = s;
      continue;
    }
    k -= 640;
    {                                 // wpTb[h][d] = Wp[d][h], bf16 [64][512]
      int h = k >> 9, d = k & 511;
      wpTb[k] = (bf16)Wp[d * 64 + h];
    }
  }
}

// ---------------------------------------------------------------- generic GEMM
// C[M,N] = A[M,K](bf16) @ B[K,N](bf16) (+bias), 64x64 tiles, 4 waves of 32x32.
// xout != nullptr: additionally write bf16 result into ugb layout (c12 -> gate input).
__global__ __launch_bounds__(256, 2) void k_gemm(
    const bf16* __restrict__ A, int lda, long asz,
    const bf16* __restrict__ B, int ldb, long bsz,
    float* __restrict__ C, int ldc, long csz,
    const float* __restrict__ bias, int bstride, int K,
    bf16* __restrict__ xout)
{
  __shared__ bf16 As[64 * 40];
  __shared__ bf16 Bs[64 * 40];
  const int t = threadIdx.x, lane = t & 63, wave = t >> 6;
  const int tc = blockIdx.x, tr = blockIdx.y, z = blockIdx.z;
  A += (long)z * asz; B += (long)z * bsz; C += (long)z * csz;
  const int wr = wave >> 1, wc = wave & 1;
  const int arow = t >> 2, aslot = t & 3;
  const int s = lane >> 4, rr = lane & 15;
  f32x4 acc00 = {}, acc01 = {}, acc10 = {}, acc11 = {};
  const int nk = K >> 5;
  for (int kk = 0; kk < nk; ++kk) {
    __syncthreads();
    *(uint4*)&As[arow * 40 + aslot * 8] =
        *(const uint4*)(A + (long)(tr * 64 + arow) * lda + kk * 32 + aslot * 8);
    {
      const bf16* bsrc = B + (long)(kk * 32 + aslot * 8) * ldb + tc * 64 + arow;
      bf16x8 tv;
#pragma unroll
      for (int e = 0; e < 8; ++e) tv[e] = bsrc[(long)e * ldb];
      *(bf16x8*)&Bs[arow * 40 + aslot * 8] = tv;
    }
    __syncthreads();
    bf16x8 a0 = *(const bf16x8*)&As[(wr * 32 + rr) * 40 + s * 8];
    bf16x8 a1 = *(const bf16x8*)&As[(wr * 32 + 16 + rr) * 40 + s * 8];
    bf16x8 b0 = *(const bf16x8*)&Bs[(wc * 32 + rr) * 40 + s * 8];
    bf16x8 b1 = *(const bf16x8*)&Bs[(wc * 32 + 16 + rr) * 40 + s * 8];
    acc00 = MFMA16(a0, b0, acc00);
    acc01 = MFMA16(a0, b1, acc01);
    acc10 = MFMA16(a1, b0, acc10);
    acc11 = MFMA16(a1, b1, acc11);
  }
#pragma unroll
  for (int mf = 0; mf < 2; ++mf) {
#pragma unroll
    for (int nf = 0; nf < 2; ++nf) {
      f32x4 v = mf == 0 ? (nf == 0 ? acc00 : acc01) : (nf == 0 ? acc10 : acc11);
      int col = tc * 64 + wc * 32 + nf * 16 + rr;
      float bi = bias ? bias[z * bstride + col] : 0.f;
      int row0 = tr * 64 + wr * 32 + mf * 16 + s * 4;
#pragma unroll
      for (int r = 0; r < 4; ++r) {
        float val = v[r] + bi;
        int row = row0 + r;
        C[(long)row * ldc + col] = val;
        if (xout) {
          long gidx = (row < 512)
              ? ((long)row * 1024 + 512 + col)
              : (524288 + (long)(row - 512) * 1024 + 512 + col);
          xout[gidx] = (bf16)val;
        }
      }
    }
  }
}

// ---------------------------------------------------------------- fused pair scorer
// One WG per i; 8 waves; wave w owns j in [w*64, w*64+64). Double-buffered 32-d chunks.
// docopy: grid-strided float4 copy of all_span_vecs -> out_all appended at the tail.
__global__ __launch_bounds__(512, 2) void k_pair(
    const bf16* __restrict__ Ubf, const float* __restrict__ Uf,
    const bf16* __restrict__ wpTb, const float* __restrict__ LR,
    const float* __restrict__ dtabg, const int* __restrict__ sb,
    const float* __restrict__ ss, const float* __restrict__ Wo,
    const float* __restrict__ bo, float* __restrict__ cs,
    const float* __restrict__ copysrc, float* __restrict__ copydst, int docopy)
{
  __shared__ bf16 As[2][512 * 32];  // 2 x 32KB, row = 64B = 4 x 16B slots
  __shared__ bf16 Vs[2][64 * 32];   // 2 x 4KB
  __shared__ float uil[512];
  __shared__ float dts[640];

  const int t = threadIdx.x;
  const int l = t & 63;
  const int w = t >> 6;
  const int i = blockIdx.x;
  const int half = l >> 5;
  const int l31 = l & 31;

  // ---- prologue: u_i row (f32) + dist table
  if (t < 128) {
    float4 v = *(const float4*)(Uf + (long)i * 512 + t * 4);
    *(float4*)&uil[t * 4] = v;
  }
  for (int idx = t; idx < 640; idx += 512) dts[idx] = dtabg[idx];

  const bf16 *asrc0, *asrc1, *asrc2, *asrc3;
  {
    int rq0 = 0 * 128 + (t >> 2), rq1 = 1 * 128 + (t >> 2);
    int rq2 = 2 * 128 + (t >> 2), rq3 = 3 * 128 + (t >> 2);
    asrc0 = Ubf + (long)rq0 * 512 + (((t & 3) ^ ((rq0 >> 1) & 3)) * 8);
    asrc1 = Ubf + (long)rq1 * 512 + (((t & 3) ^ ((rq1 >> 1) & 3)) * 8);
    asrc2 = Ubf + (long)rq2 * 512 + (((t & 3) ^ ((rq2 >> 1) & 3)) * 8);
    asrc3 = Ubf + (long)rq3 * 512 + (((t & 3) ^ ((rq3 >> 1) & 3)) * 8);
  }
  int aoff[2][2], voff[2][2];
#pragma unroll
  for (int jf = 0; jf < 2; ++jf)
#pragma unroll
    for (int ks = 0; ks < 2; ++ks) {
      int r = w * 64 + jf * 32 + l31;
      aoff[jf][ks] = r * 64 + (((ks * 2 + half) ^ ((r >> 1) & 3)) * 16);
    }
#pragma unroll
  for (int hf = 0; hf < 2; ++hf)
#pragma unroll
    for (int ks = 0; ks < 2; ++ks) {
      int h = hf * 32 + l31;
      voff[hf][ks] = h * 64 + (((ks * 2 + half) ^ ((h >> 1) & 3)) * 16);
    }
  const int vh = t >> 2;
  const int vcp = (t & 3) ^ ((vh >> 1) & 3);

  __syncthreads();   // uil visible before V builds

  // ---- stage chunk 0 into buf 0
  gll16(asrc0, &As[0][0 * 4096 + w * 512]);
  gll16(asrc1, &As[0][1 * 4096 + w * 512]);
  gll16(asrc2, &As[0][2 * 4096 + w * 512]);
  gll16(asrc3, &As[0][3 * 4096 + w * 512]);
  if (t < 256) {
    bf16x8 wv = *(const bf16x8*)(wpTb + (long)vh * 512 + vcp * 8);
    float4 u0 = *(const float4*)&uil[vcp * 8];
    float4 u1 = *(const float4*)&uil[vcp * 8 + 4];
    bf16x8 sv8;
#pragma unroll
    for (int e = 0; e < 4; ++e) {
      sv8[e] = (bf16)((float)wv[e] * u0[e]);
      sv8[e + 4] = (bf16)((float)wv[e + 4] * u1[e]);
    }
    *(bf16x8*)((char*)&Vs[0][0] + vh * 64 + (t & 3) * 16) = sv8;
  }
  asm volatile("s_waitcnt vmcnt(0)");
  __syncthreads();

  f32x16 acc[2][2] = {};

  for (int kc = 0; kc < 16; ++kc) {
    const int cur = kc & 1;
    if (kc < 15) {
      gll16(asrc0 + (kc + 1) * 32, &As[cur ^ 1][0 * 4096 + w * 512]);
      gll16(asrc1 + (kc + 1) * 32, &As[cur ^ 1][1 * 4096 + w * 512]);
      gll16(asrc2 + (kc + 1) * 32, &As[cur ^ 1][2 * 4096 + w * 512]);
      gll16(asrc3 + (kc + 1) * 32, &As[cur ^ 1][3 * 4096 + w * 512]);
      if (t < 256) {
        bf16x8 wv = *(const bf16x8*)(wpTb + (long)vh * 512 + (kc + 1) * 32 + vcp * 8);
        float4 u0 = *(const float4*)&uil[(kc + 1) * 32 + vcp * 8];
        float4 u1 = *(const float4*)&uil[(kc + 1) * 32 + vcp * 8 + 4];
        bf16x8 sv8;
#pragma unroll
        for (int e = 0; e < 4; ++e) {
          sv8[e] = (bf16)((float)wv[e] * u0[e]);
          sv8[e + 4] = (bf16)((float)wv[e + 4] * u1[e]);
        }
        *(bf16x8*)((char*)&Vs[cur ^ 1][0] + vh * 64 + (t & 3) * 16) = sv8;
      }
    }
    const char* Asb = (const char*)&As[cur][0];
    const char* Vsb = (const char*)&Vs[cur][0];
#pragma unroll
    for (int ks = 0; ks < 2; ++ks) {
      bf16x8 af0 = *(const bf16x8*)(Asb + aoff[0][ks]);
      bf16x8 af1 = *(const bf16x8*)(Asb + aoff[1][ks]);
      bf16x8 vf0 = *(const bf16x8*)(Vsb + voff[0][ks]);
      bf16x8 vf1 = *(const bf16x8*)(Vsb + voff[1][ks]);
      __builtin_amdgcn_s_setprio(1);
      acc[0][0] = MFMA32(af0, vf0, acc[0][0]);
      acc[0][1] = MFMA32(af0, vf1, acc[0][1]);
      acc[1][0] = MFMA32(af1, vf0, acc[1][0]);
      acc[1][1] = MFMA32(af1, vf1, acc[1][1]);
      __builtin_amdgcn_s_setprio(0);
    }
    if (kc < 15) asm volatile("s_waitcnt vmcnt(0)");
    __syncthreads();
  }

  // ---- epilogue
  const float lf0 = LR[i * 128 + l31];
  const float lf1 = LR[i * 128 + 32 + l31];
  const float wo0 = Wo[l31], wo1 = Wo[32 + l31];
  const int sbi = sb[i];
  const float ssi = ss[i];
  const float bo0 = bo[0];
#pragma unroll
  for (int jf = 0; jf < 2; ++jf) {
#pragma unroll
    for (int r = 0; r < 16; ++r) {
      int j = w * 64 + jf * 32 + (r & 3) + 8 * (r >> 2) + 4 * half;
      int dd = sbi - sb[j];
      int ad = dd < 0 ? -dd : dd;
      int bkt = ad < 5 ? ad : (31 - __clz(ad)) + 3;
      bkt = bkt > 9 ? 9 : bkt;
      float v0 = fmaxf(acc[jf][0][r] + lf0 + LR[j * 128 + 64 + l31] +
                       dts[bkt * 64 + l31], 0.f);
      float v1 = fmaxf(acc[jf][1][r] + lf1 + LR[j * 128 + 96 + l31] +
                       dts[bkt * 64 + 32 + l31], 0.f);
      float sum = v0 * wo0 + v1 * wo1;
      sum += __shfl_xor(sum, 1);
      sum += __shfl_xor(sum, 2);
      sum += __shfl_xor(sum, 4);
      sum += __shfl_xor(sum, 8);
      sum += __shfl_xor(sum, 16);
      if (l31 == 0)
        cs[(long)i * 512 + j] = (j == i) ? 0.f : (sum + bo0 + ssi + ss[j]);
    }
  }

  // ---- folded all_span_vecs copy (rides idle HBM pipe)
  if (docopy) {
    const float4* s4 = (const float4*)copysrc;
    float4* d4 = (float4*)copydst;
    int idx = i * 512 + t;               // 262144 threads
#pragma unroll
    for (int q = 0; q < 8; ++q)
      d4[(long)q * 262144 + idx] = s4[(long)q * 262144 + idx];
  }
}

// ---------------------------------------------------------------- masked softmax rows
__global__ __launch_bounds__(64) void k_softmax(const float* __restrict__ cs,
                                                bf16* __restrict__ p12)
{
  int b = blockIdx.x, kind = b >> 9, i = b & 511, lane = threadIdx.x;
  const float* row = cs + i * 512;
  float v[8];
  float4 x0 = *(const float4*)(row + lane * 8);
  float4 x1 = *(const float4*)(row + lane * 8 + 4);
  v[0] = x0.x; v[1] = x0.y; v[2] = x0.z; v[3] = x0.w;
  v[4] = x1.x; v[5] = x1.y; v[6] = x1.z; v[7] = x1.w;
  bool any = (kind == 0) ? (i > 0) : (i < 511);
  bf16x8 ov;
  if (!any) {
    float u = 1.0f / 512.0f;
#pragma unroll
    for (int e = 0; e < 8; ++e) ov[e] = (bf16)u;
  } else {
    float m = -3.4e38f;
#pragma unroll
    for (int e = 0; e < 8; ++e) {
      int jj = lane * 8 + e;
      bool valid = (kind == 0) ? (jj < i) : (jj > i);
      if (valid) m = fmaxf(m, v[e]);
    }
    m = fmaxf(m, __shfl_xor(m, 1));  m = fmaxf(m, __shfl_xor(m, 2));
    m = fmaxf(m, __shfl_xor(m, 4));  m = fmaxf(m, __shfl_xor(m, 8));
    m = fmaxf(m, __shfl_xor(m, 16)); m = fmaxf(m, __shfl_xor(m, 32));
    float p[8]; float ssum = 0.f;
#pragma unroll
    for (int e = 0; e < 8; ++e) {
      int jj = lane * 8 + e;
      bool valid = (kind == 0) ? (jj < i) : (jj > i);
      p[e] = valid ? __expf(v[e] - m) : 0.f;
      ssum += p[e];
    }
    ssum += __shfl_xor(ssum, 1);  ssum += __shfl_xor(ssum, 2);
    ssum += __shfl_xor(ssum, 4);  ssum += __shfl_xor(ssum, 8);
    ssum += __shfl_xor(ssum, 16); ssum += __shfl_xor(ssum, 32);
    float inv = 1.0f / ssum;
#pragma unroll
    for (int e = 0; e < 8; ++e) ov[e] = (bf16)(p[e] * inv);
  }
  *(bf16x8*)(p12 + (long)b * 512 + lane * 8) = ov;
}

// ---------------------------------------------------------------- mid2: gate+ss2+lr2+scatter
// One WG per row i, 512 threads (thread t = dim d).
__global__ __launch_bounds__(512) void k_mid2(
    const float* __restrict__ sv, const float* __restrict__ c12,
    const float* __restrict__ G12, const float* __restrict__ Wpr,
    const float* __restrict__ bpr, const bf16* __restrict__ wlr,
    const float* __restrict__ blbr, const int* __restrict__ pi,
    const int* __restrict__ sl, float* __restrict__ upd,
    bf16* __restrict__ u2, float* __restrict__ ss2,
    float* __restrict__ lr2, float* __restrict__ out_all)
{
  __shared__ float upl[512];
  __shared__ float red[8];
  __shared__ float part2[4][128];
  const int i = blockIdx.x;
  const int t = threadIdx.x;
  const long ii = (long)i * 512 + t;

  float u = sv[ii], c1 = c12[ii], c2 = c12[262144 + ii];
  float g1 = 1.f / (1.f + __expf(-G12[ii]));
  float g2 = 1.f / (1.f + __expf(-G12[262144 + ii]));
  float up = g1 * u + (1.f - g1) * c1 + g2 * u + (1.f - g2) * c2;
  upd[ii] = up;
  u2[ii] = (bf16)up;
  upl[t] = up;
  if (i < sl[0]) out_all[(long)pi[i] * 512 + t] = up;   // scatter (out_all pre-filled)

  // ss2 = dot(up, Wpr) + bpr
  float pd = up * Wpr[t];
  pd += __shfl_xor(pd, 1);  pd += __shfl_xor(pd, 2);  pd += __shfl_xor(pd, 4);
  pd += __shfl_xor(pd, 8);  pd += __shfl_xor(pd, 16); pd += __shfl_xor(pd, 32);
  if ((t & 63) == 0) red[t >> 6] = pd;
  __syncthreads();
  if (t == 0) {
    float s = 0.f;
#pragma unroll
    for (int e = 0; e < 8; ++e) s += red[e];
    ss2[i] = s + bpr[0];
  }

  // lr2[i][n] = sum_d up[d]*wlr[d][n] + blbr[n]; 4 k-parts x 128 n
  const int n = t & 127, part = t >> 7;
  float s = 0.f;
  const int d0 = part * 128;
#pragma unroll 4
  for (int d2 = 0; d2 < 128; ++d2)
    s += upl[d0 + d2] * (float)wlr[(d0 + d2) * 128 + n];
  part2[part][n] = s;
  __syncthreads();
  if (t < 128)
    lr2[(long)i * 128 + t] =
        part2[0][t] + part2[1][t] + part2[2][t] + part2[3][t] + blbr[t];
}

// ---------------------------------------------------------------- launch
extern "C" void kernel_launch(void* const* d_in, const int* in_sizes, int n_in,
                              void* d_out, int out_size, void* d_ws, size_t ws_size,
                              hipStream_t stream)
{
  const float* asv = (const float*)d_in[0];
  const float* sv = (const float*)d_in[1];
  const int* sb = (const int*)d_in[2];
  const float* sscore = (const float*)d_in[5];
  const int* pi = (const int*)d_in[6];
  const int* sl = (const int*)d_in[7];
  const float* Wl = (const float*)d_in[9];
  const float* bl = (const float*)d_in[10];
  const float* Wr = (const float*)d_in[11];
  const float* br = (const float*)d_in[12];
  const float* Wp = (const float*)d_in[13];
  const float* de = (const float*)d_in[14];
  const float* Wd = (const float*)d_in[15];
  const float* bd = (const float*)d_in[16];
  const float* Wo = (const float*)d_in[17];
  const float* bo = (const float*)d_in[18];
  const float* Wg1 = (const float*)d_in[19];
  const float* bg1 = (const float*)d_in[20];
  const float* Wg2 = (const float*)d_in[21];
  const float* bg2 = (const float*)d_in[22];
  const float* Wpr = (const float*)d_in[23];
  const float* bpr = (const float*)d_in[24];

  float* out_all = (float*)d_out;
  float* out_upd = out_all + 8388608;   // [512][512] update
  float* out_cs = out_all + 8650752;    // [512][512] cs

  char* w = (char*)d_ws;
  size_t off = 0;
  auto take = [&](size_t bytes) -> void* {
    void* p = w + off;
    off = (off + bytes + 255) & ~(size_t)255;
    return p;
  };
  bf16* u1b = (bf16*)take(524288);
  bf16* u2b = (bf16*)take(524288);
  bf16* wlr = (bf16*)take(131072);
  bf16* wgb = (bf16*)take(2097152);
  float* blbr = (float*)take(512);
  float* bgc = (float*)take(4096);
  float* dtab = (float*)take(2560);
  bf16* wpTb = (bf16*)take(65536);
  float* lr1 = (float*)take(262144);
  float* lr2 = (float*)take(262144);
  float* cs1 = (float*)take(1048576);
  bf16* p12 = (bf16*)take(1048576);
  float* c12 = (float*)take(4194304);
  bf16* ugb = (bf16*)take(2097152);
  float* G12 = (float*)take(2097152);
  float* ss2 = (float*)take(2048);

  k_prep<<<2048, 256, 0, stream>>>(sv, Wl, Wr, Wg1, Wg2, de, Wd, bd, bl, br, bg1, bg2,
                                   Wp, u1b, ugb, wlr, blbr, bgc, wgb, dtab, wpTb);
  // left|right for u
  k_gemm<<<dim3(2, 8, 1), 256, 0, stream>>>(u1b, 512, 0, wlr, 128, 0, lr1, 128, 0,
                                            blbr, 0, 512, nullptr);
  // cs1 = add_scores(pair_scores(u), span_scores); + full all_out copy
  k_pair<<<512, 512, 0, stream>>>(u1b, sv, wpTb, lr1, dtab, sb, sscore, Wo, bo, cs1,
                                  asv, out_all, 1);
  // p1,p2
  k_softmax<<<1024, 64, 0, stream>>>(cs1, p12);
  // c1,c2 = [p1;p2] @ u ; epilogue also fills ugb right halves (bf16)
  k_gemm<<<dim3(8, 16, 1), 256, 0, stream>>>(p12, 512, 0, u1b, 512, 0, c12, 512, 0,
                                             nullptr, 0, 512, ugb);
  // G1,G2 = [u|c] @ Wg + bg   (batched z=2, K=1024)
  k_gemm<<<dim3(8, 8, 2), 256, 0, stream>>>(ugb, 1024, 524288, wgb, 512, 524288,
                                            G12, 512, 262144, bgc, 512, 1024, nullptr);
  // update + u2 bf16 + ss2 + lr2 + scatter (fused)
  k_mid2<<<512, 512, 0, stream>>>(sv, c12, G12, Wpr, bpr, wlr, blbr, pi, sl,
                                  out_upd, u2b, ss2, lr2, out_all);
  // cs = add_scores(pair_scores(update), update@Wpr+bpr)
  k_pair<<<512, 512, 0, stream>>>(u2b, out_upd, wpTb, lr2, dtab, sb, ss2, Wo, bo,
                                  out_cs, nullptr, nullptr, 0);
}